// Round 4
// baseline (1401.280 us; speedup 1.0000x reference)
//
#include <hip/hip_runtime.h>
#include <stdint.h>

// ---------------------------------------------------------------------------
// Node_GCN: PAE edge weights (MLP+BN+dropout+cosine) -> 2x GCNConv -> MLP head
// R4: (1) pae VALU diet: v_alignbit rotates in threefry, v_perm bf16 pack,
//     full kt unroll. (2) GCN aggregation switched from 64M-atomic scatter to
//     per-call CSR build (hist/scan/fill) + one-wave-per-node gather with
//     fused self-loop+bias+relu (conv_finalize and BUFB memsets removed).
// Workspace (floats): [bn_sums 512][pad][EW 1e6][DINV 1e5][BUFA 6.4e6]
//   [BUFB 6.4e6][PTR NN+1][FILL NN][EIDX NE][CNT NN][BSUM 391]  ~60.6 MB
// ---------------------------------------------------------------------------

#define NN 100000
#define NE 1000000
#define INV_KEEP (1.0f/0.7f)
// uniform(bits) < 0.7  <=>  bits < 5872026<<9   (0.7f = 0x3F333333 exactly)
#define KEEP_THR 3006477312u

typedef short bf16x8 __attribute__((ext_vector_type(8)));
typedef float f32x4  __attribute__((ext_vector_type(4)));
typedef uint32_t u32x4 __attribute__((ext_vector_type(4)));

// ---- threefry2x32 (20 rounds), exact jax/_src/prng.py semantics -----------
__host__ __device__ constexpr uint32_t rotl32c(uint32_t x, int r) {
  return (x << r) | (x >> (32 - r));
}

struct TFK { uint32_t a, b; };
__host__ __device__ constexpr TFK tf_const(uint32_t k0, uint32_t k1,
                                           uint32_t x0, uint32_t x1) {
  uint32_t k2 = k0 ^ k1 ^ 0x1BD11BDAu;
  x0 += k0; x1 += k1;
#define TFC_R(r) { x0 += x1; x1 = rotl32c(x1, (r)); x1 ^= x0; }
  TFC_R(13) TFC_R(15) TFC_R(26) TFC_R(6)   x0 += k1; x1 += k2 + 1u;
  TFC_R(17) TFC_R(29) TFC_R(16) TFC_R(24)  x0 += k2; x1 += k0 + 2u;
  TFC_R(13) TFC_R(15) TFC_R(26) TFC_R(6)   x0 += k0; x1 += k1 + 3u;
  TFC_R(17) TFC_R(29) TFC_R(16) TFC_R(24)  x0 += k1; x1 += k2 + 4u;
  TFC_R(13) TFC_R(15) TFC_R(26) TFC_R(6)   x0 += k2; x1 += k0 + 5u;
#undef TFC_R
  return TFK{x0, x1};
}

// keys from jax.random.split(jax.random.key(42)), partitionable mode
constexpr TFK KP = tf_const(0u, 42u, 0u, 0u);
constexpr TFK KH = tf_const(0u, 42u, 0u, 1u);

// partitionable random bits for element idx: threefry(key,(0,idx)) -> o0^o1
// rotate via v_alignbit_b32 (1 instr) instead of shl+shr+or (3 instr).
template <uint32_t K0, uint32_t K1>
__device__ __forceinline__ uint32_t tf_bits(uint32_t idx) {
  constexpr uint32_t K2 = K0 ^ K1 ^ 0x1BD11BDAu;
  uint32_t x0 = K0;
  uint32_t x1 = idx + K1;
#define TF_R(r) { x0 += x1; \
    x1 = __builtin_amdgcn_alignbit(x1, x1, 32u - (r)) ^ x0; }
  TF_R(13) TF_R(15) TF_R(26) TF_R(6)   x0 += K1; x1 += K2 + 1u;
  TF_R(17) TF_R(29) TF_R(16) TF_R(24)  x0 += K2; x1 += K0 + 2u;
  TF_R(13) TF_R(15) TF_R(26) TF_R(6)   x0 += K0; x1 += K1 + 3u;
  TF_R(17) TF_R(29) TF_R(16) TF_R(24)  x0 += K1; x1 += K2 + 4u;
  TF_R(13) TF_R(15) TF_R(26) TF_R(6)   x0 += K2; x1 += K0 + 5u;
#undef TF_R
  return x0 ^ x1;
}

__device__ __forceinline__ uint16_t f2bf(float f) {  // RNE (cold paths only)
  uint32_t u = __float_as_uint(f);
  return (uint16_t)((u + 0x7FFFu + ((u >> 16) & 1u)) >> 16);
}

// ---------------------------------------------------------------------------
// K1: BN statistics, sync-free wave-uniform loads. 1000 blocks x 1000 edges.
// ---------------------------------------------------------------------------
__global__ __launch_bounds__(256) void bn_stats(const float* __restrict__ edgenet,
                                                const float* __restrict__ w1,
                                                const float* __restrict__ b1,
                                                float* __restrict__ sums) {
  int t = threadIdx.x;
  int c = t & 127, s = t >> 7;
  float wA = w1[c], wB = w1[128 + c], bb = b1[c];
  const float2* ed2 = (const float2*)edgenet;
  int e0 = blockIdx.x * 1000;
  float sm0 = 0.f, sm1 = 0.f, q0 = 0.f, q1 = 0.f;
#pragma unroll 4
  for (int e = 0; e < 1000; e += 2) {
    float2 xa = ed2[(e0 + e) * 2 + s];
    float2 xb = ed2[(e0 + e + 1) * 2 + s];
    float h = fmaxf(fmaf(xa.y, wB, fmaf(xa.x, wA, bb)), 0.f);
    sm0 += h; q0 = fmaf(h, h, q0);
    h = fmaxf(fmaf(xb.y, wB, fmaf(xb.x, wA, bb)), 0.f);
    sm1 += h; q1 = fmaf(h, h, q1);
  }
  atomicAdd(&sums[t], sm0 + sm1);
  atomicAdd(&sums[256 + t], q0 + q1);
}

// ---------------------------------------------------------------------------
// K2: finalize -> packed param table PRM (896 floats):
//   [0]wA[128] [128]wB[128] [256]b1[128] [384]aK[256] [640]bK[256]
// aK/bK: BN affine with INV_KEEP folded in (per half s).
// ---------------------------------------------------------------------------
__global__ void bn_finalize(const float* __restrict__ sums,
                            const float* __restrict__ w1,
                            const float* __restrict__ b1,
                            const float* __restrict__ gamma,
                            const float* __restrict__ beta,
                            float* __restrict__ prm) {
  int t = threadIdx.x;  // 256
  int c = t & 127;
  const float invE = 1.0f / (float)NE;
  float mean = sums[t] * invE;
  float var = fmaxf(sums[256 + t] * invE - mean * mean, 0.f);
  float rstd = rsqrtf(var + 1e-5f);
  float a = gamma[c] * rstd;
  prm[384 + t] = a * INV_KEEP;
  prm[640 + t] = (beta[c] - mean * a) * INV_KEEP;
  if (t < 128) { prm[t] = w1[t]; prm[128 + t] = w1[128 + t]; prm[256 + t] = b1[t]; }
}

// ---------------------------------------------------------------------------
// K2b: w2 -> bf16 transposed [n][k] for MFMA B-operand.
// ---------------------------------------------------------------------------
__global__ void w2_prep(const float* __restrict__ w2, uint32_t* __restrict__ w2t) {
  int i = blockIdx.x * 256 + threadIdx.x;  // < 8192, one uint = 2 bf16 along k
  int n = i >> 6, kp = i & 63;
  float f0 = w2[(2 * kp) * 128 + n];
  float f1 = w2[(2 * kp + 1) * 128 + n];
  w2t[i] = (uint32_t)f2bf(f0) | ((uint32_t)f2bf(f1) << 16);
}

// ---------------------------------------------------------------------------
// K3: PAE fused, fragment-direct. 32 edges/block (64 rows), 4 waves.
// Lane (cl,quad): row=16w+cl, channels c = kt*32+quad*8+j straight into the
// A fragment. B (w2t bf16 [n][k]) in LDS. Epilogue: cosine + fused deg atomic.
// ---------------------------------------------------------------------------
__global__ __launch_bounds__(256, 3) void pae_edge(const float* __restrict__ edgenet,
                                                const float* __restrict__ prm_g,
                                                const uint32_t* __restrict__ w2t,
                                                const float* __restrict__ b2,
                                                const int* __restrict__ colp,
                                                float* __restrict__ ew_out,
                                                float* __restrict__ deg) {
  __shared__ __align__(16) uint16_t w2s[128 * 136];  // B tile [n][k], +8 pad
  __shared__ __align__(16) float prm[896];
  __shared__ float b2s[128];
  int t = threadIdx.x;
  int e0 = blockIdx.x * 32;
  for (int i = t; i < 8192; i += 256) {               // stage w2t -> LDS
    int n = i >> 6, kp = i & 63;
    *(uint32_t*)&w2s[n * 136 + 2 * kp] = w2t[i];
  }
  for (int i = t; i < 896; i += 256) prm[i] = prm_g[i];
  if (t < 128) b2s[t] = b2[t];
  __syncthreads();

  int lane = t & 63, w = t >> 6;
  int cl = lane & 15, quad = lane >> 4;
  int quad8 = quad * 8;
  int row = 16 * w + cl;
  int el = row >> 1, s = row & 1;
  int so = s << 7;                                    // s*128
  float2 xv = *(const float2*)&edgenet[(size_t)(e0 + el) * 4 + 2 * s];
  uint32_t rowbase = (uint32_t)(e0 + el) * 128u + (s ? 128000000u : 0u);

  f32x4 acc[8];
#pragma unroll
  for (int nt = 0; nt < 8; ++nt) acc[nt] = (f32x4){0.f, 0.f, 0.f, 0.f};

#pragma unroll
  for (int kt = 0; kt < 4; ++kt) {
    int c0 = kt * 32 + quad8;
    uint32_t idxbase = rowbase + (uint32_t)c0;
    float wa[8], wb[8], bb[8], ak[8], bk[8];
    *(float4*)&wa[0] = *(const float4*)&prm[c0];
    *(float4*)&wa[4] = *(const float4*)&prm[c0 + 4];
    *(float4*)&wb[0] = *(const float4*)&prm[128 + c0];
    *(float4*)&wb[4] = *(const float4*)&prm[132 + c0];
    *(float4*)&bb[0] = *(const float4*)&prm[256 + c0];
    *(float4*)&bb[4] = *(const float4*)&prm[260 + c0];
    *(float4*)&ak[0] = *(const float4*)&prm[384 + so + c0];
    *(float4*)&ak[4] = *(const float4*)&prm[388 + so + c0];
    *(float4*)&bk[0] = *(const float4*)&prm[640 + so + c0];
    *(float4*)&bk[4] = *(const float4*)&prm[644 + so + c0];
    uint32_t pk[4];
#pragma unroll
    for (int jp = 0; jp < 4; ++jp) {
      uint32_t u[2];
#pragma unroll
      for (int q = 0; q < 2; ++q) {
        int j = 2 * jp + q;
        float h = fmaxf(fmaf(xv.y, wb[j], fmaf(xv.x, wa[j], bb[j])), 0.f);
        float hn = fmaf(h, ak[j], bk[j]);
        uint32_t bits = tf_bits<KP.a, KP.b>(idxbase + (uint32_t)j);
        float hd = (bits < KEEP_THR) ? hn : 0.f;
        u[q] = __float_as_uint(hd) + 0x8000u;
      }
      // pk = hi16(u0) | hi16(u1)<<16  via one v_perm_b32
      pk[jp] = __builtin_amdgcn_perm(u[1], u[0], 0x07060302u);
    }
    u32x4 pkv = {pk[0], pk[1], pk[2], pk[3]};
    bf16x8 afr = __builtin_bit_cast(bf16x8, pkv);
    const uint16_t* bbase = &w2s[(size_t)c0];
#pragma unroll
    for (int nt = 0; nt < 8; ++nt) {
      bf16x8 bfr = *(const bf16x8*)&bbase[(nt * 16 + cl) * 136];
      acc[nt] = __builtin_amdgcn_mfma_f32_16x16x32_bf16(afr, bfr, acc[nt], 0, 0, 0);
    }
  }

  // epilogue: lane holds C rows quad*4+{0..3} (edge pairs), col nt*16+cl
  float p11[2] = {0.f, 0.f}, p22[2] = {0.f, 0.f}, p12[2] = {0.f, 0.f};
#pragma unroll
  for (int nt = 0; nt < 8; ++nt) {
    float bv = b2s[nt * 16 + cl];
#pragma unroll
    for (int u = 0; u < 2; ++u) {
      float v1 = acc[nt][2 * u] + bv;
      float v2 = acc[nt][2 * u + 1] + bv;
      p11[u] = fmaf(v1, v1, p11[u]);
      p22[u] = fmaf(v2, v2, p22[u]);
      p12[u] = fmaf(v1, v2, p12[u]);
    }
  }
#pragma unroll
  for (int u = 0; u < 2; ++u) {
    float a = p11[u], b = p22[u], d = p12[u];
    for (int off = 1; off < 16; off <<= 1) {
      a += __shfl_xor(a, off, 64);
      b += __shfl_xor(b, off, 64);
      d += __shfl_xor(d, off, 64);
    }
    if (cl == 0) {
      int e = e0 + 8 * w + 2 * quad + u;
      float n1 = fmaxf(sqrtf(a), 1e-8f);
      float n2 = fmaxf(sqrtf(b), 1e-8f);
      float ew = (d / (n1 * n2) + 1.f) * 0.5f;
      ew_out[e] = ew;
      atomicAdd(&deg[colp[e]], ew);   // fused degree scatter
    }
  }
}

// ---------------------------------------------------------------------------
// CSR build: hist -> 2-level exclusive scan -> fill
// ---------------------------------------------------------------------------
__global__ void csr_hist(const int* __restrict__ col, int* __restrict__ cnt) {
  int e = blockIdx.x * 256 + threadIdx.x;
  if (e < NE) atomicAdd(&cnt[col[e]], 1);
}

__global__ __launch_bounds__(256) void csr_scanA(const int* __restrict__ cnt,
                                                 int* __restrict__ ptr,
                                                 int* __restrict__ bsum) {
  __shared__ int sh[256];
  int t = threadIdx.x;
  int i = blockIdx.x * 256 + t;
  int x = (i < NN) ? cnt[i] : 0;
  sh[t] = x;
  __syncthreads();
  for (int o = 1; o < 256; o <<= 1) {
    int v = (t >= o) ? sh[t - o] : 0;
    __syncthreads();
    sh[t] += v;
    __syncthreads();
  }
  if (i < NN) ptr[i] = sh[t] - x;          // exclusive within block
  if (t == 255) bsum[blockIdx.x] = sh[255];
}

__global__ __launch_bounds__(512) void csr_scanB(int* __restrict__ bsum) {
  __shared__ int sh[512];
  int t = threadIdx.x;
  int x = (t < 391) ? bsum[t] : 0;
  sh[t] = x;
  __syncthreads();
  for (int o = 1; o < 512; o <<= 1) {
    int v = (t >= o) ? sh[t - o] : 0;
    __syncthreads();
    sh[t] += v;
    __syncthreads();
  }
  if (t < 391) bsum[t] = sh[t] - x;        // exclusive block offsets
}

__global__ void csr_scanAdd(int* __restrict__ ptr, const int* __restrict__ bsum,
                            int* __restrict__ fill) {
  int i = blockIdx.x * 256 + threadIdx.x;
  if (i < NN) {
    int v = ptr[i] + bsum[blockIdx.x];
    ptr[i] = v;
    fill[i] = v;
    if (i == NN - 1) ptr[NN] = NE;
  }
}

__global__ void csr_fill(const int* __restrict__ col, int* __restrict__ fill,
                         int* __restrict__ eidx) {
  int e = blockIdx.x * 256 + threadIdx.x;
  if (e < NE) {
    int p = atomicAdd(&fill[col[e]], 1);
    eidx[p] = e;
  }
}

// ---------------------------------------------------------------------------
// K5: deg -> dinv (self-loop weight 1 folded in)
// ---------------------------------------------------------------------------
__global__ void deg_to_dinv(float* __restrict__ deg) {
  int v = blockIdx.x * 256 + threadIdx.x;
  if (v < NN) deg[v] = rsqrtf(deg[v] + 1.0f);
}

// ---------------------------------------------------------------------------
// K6: feature GEMM [N,64]@[64,64] -> out (no bias). 64 nodes/block, 4x4 tiles.
// ---------------------------------------------------------------------------
__global__ __launch_bounds__(256) void gemm_feat(const float* __restrict__ in,
                                                 const float* __restrict__ W,
                                                 float* __restrict__ out, int n) {
  __shared__ __align__(16) float InT[64 * 68];
  __shared__ __align__(16) float Wl[64 * 64];
  int t = threadIdx.x;
  int v0 = blockIdx.x * 64;
  for (int i = t; i < 4096; i += 256) {
    Wl[i] = W[i];
    int v = i >> 6, k = i & 63;
    int vv = min(v0 + v, n - 1);
    InT[k * 68 + v] = in[vv * 64 + k];
  }
  __syncthreads();
  int tx = t & 15, ty = t >> 4;
  float acc[4][4];
#pragma unroll
  for (int i = 0; i < 4; ++i)
#pragma unroll
    for (int j = 0; j < 4; ++j) acc[i][j] = 0.f;
#pragma unroll 4
  for (int k = 0; k < 64; ++k) {
    float4 av = *(const float4*)&InT[k * 68 + 4 * ty];
    float4 bv = *(const float4*)&Wl[k * 64 + 4 * tx];
    float a4[4] = {av.x, av.y, av.z, av.w};
    float b4[4] = {bv.x, bv.y, bv.z, bv.w};
#pragma unroll
    for (int i = 0; i < 4; ++i)
#pragma unroll
      for (int j = 0; j < 4; ++j) acc[i][j] = fmaf(a4[i], b4[j], acc[i][j]);
  }
  for (int i = 0; i < 4; ++i) {
    int v = v0 + 4 * ty + i;
    if (v < n)
      *(float4*)&out[v * 64 + 4 * tx] =
          make_float4(acc[i][0], acc[i][1], acc[i][2], acc[i][3]);
  }
}

// ---------------------------------------------------------------------------
// K7: gather aggregation, one wave per node, lane = channel.
// out[v] = relu( dinv[v]*sum_e dinv[r]*ew*xw[r] + dinv[v]^2*xw[v] + bias )
// 2-deep software pipeline on edge metadata.
// ---------------------------------------------------------------------------
__global__ __launch_bounds__(256) void gather_agg(const int* __restrict__ rowp,
                                                  const int* __restrict__ ptr,
                                                  const int* __restrict__ eidx,
                                                  const float* __restrict__ ew,
                                                  const float* __restrict__ dinv,
                                                  const float* __restrict__ xw,
                                                  const float* __restrict__ bias,
                                                  float* __restrict__ out) {
  int t = threadIdx.x;
  int v = blockIdx.x * 4 + (t >> 6);
  if (v >= NN) return;
  int c = t & 63;
  int p = ptr[v], end = ptr[v + 1];
  float acc = 0.f;
  int r = 0; float cf = 0.f;
  if (p < end) {
    int e = eidx[p];
    r = rowp[e];
    cf = dinv[r] * ew[e];
  }
  while (p < end) {
    int r0 = r; float cf0 = cf;
    ++p;
    if (p < end) {
      int e = eidx[p];
      r = rowp[e];
      cf = dinv[r] * ew[e];
    }
    acc = fmaf(cf0, xw[(size_t)r0 * 64 + c], acc);
  }
  float dv = dinv[v];
  float self = dv * dv * xw[(size_t)v * 64 + c];
  float val = fmaf(dv, acc, self) + bias[c];
  out[(size_t)v * 64 + c] = fmaxf(val, 0.f);
}

// ---------------------------------------------------------------------------
// K9: MLP head: relu(h@lin1+b) -> dropout(k_head) -> @lin2+b. 8 nodes/block.
// ---------------------------------------------------------------------------
__global__ __launch_bounds__(256) void head_kernel(const float* __restrict__ h,
                                                   const float* __restrict__ l1w,
                                                   const float* __restrict__ l1b,
                                                   const float* __restrict__ l2w,
                                                   const float* __restrict__ l2b,
                                                   float* __restrict__ out) {
  __shared__ float L1[2048];
  __shared__ float L1B[32];
  __shared__ float L2[320];
  __shared__ float L2B[10];
  __shared__ float hrow[8 * 64];
  __shared__ float M[8 * 33];
  int t = threadIdx.x;
  int v0 = blockIdx.x * 8;
  for (int i = t; i < 2048; i += 256) L1[i] = l1w[i];
  if (t < 32) L1B[t] = l1b[t];
  for (int i = t; i < 320; i += 256) L2[i] = l2w[i];
  if (t < 10) L2B[t] = l2b[t];
  for (int i = t; i < 512; i += 256) hrow[i] = h[v0 * 64 + i];
  __syncthreads();

  int v = t >> 5, j = t & 31;
  float acc = L1B[j];
#pragma unroll
  for (int k = 0; k < 64; ++k) acc = fmaf(hrow[v * 64 + k], L1[k * 32 + j], acc);
  acc = fmaxf(acc, 0.f);
  uint32_t idx = (uint32_t)((v0 + v) * 32 + j);
  bool kp = tf_bits<KH.a, KH.b>(idx) < KEEP_THR;
  M[v * 33 + j] = kp ? acc * INV_KEEP : 0.f;
  __syncthreads();
  if (t < 80) {
    int vv = t / 10, f = t % 10;
    float s = L2B[f];
#pragma unroll
    for (int jj = 0; jj < 32; ++jj) s = fmaf(M[vv * 33 + jj], L2[jj * 10 + f], s);
    out[(v0 + vv) * 10 + f] = s;
  }
}

// ---------------------------------------------------------------------------
extern "C" void kernel_launch(void* const* d_in, const int* in_sizes, int n_in,
                              void* d_out, int out_size, void* d_ws, size_t ws_size,
                              hipStream_t stream) {
  const float* x       = (const float*)d_in[0];
  const int*   ei      = (const int*)d_in[1];
  const float* edgenet = (const float*)d_in[2];
  const float* pw1     = (const float*)d_in[3];
  const float* pb1     = (const float*)d_in[4];
  const float* pgamma  = (const float*)d_in[5];
  const float* pbeta   = (const float*)d_in[6];
  const float* pw2     = (const float*)d_in[7];
  const float* pb2     = (const float*)d_in[8];
  const float* c1w     = (const float*)d_in[9];
  const float* c1b     = (const float*)d_in[10];
  const float* c2w     = (const float*)d_in[11];
  const float* c2b     = (const float*)d_in[12];
  const float* l1w     = (const float*)d_in[13];
  const float* l1b     = (const float*)d_in[14];
  const float* l2w     = (const float*)d_in[15];
  const float* l2b     = (const float*)d_in[16];
  float* out = (float*)d_out;

  const int* rowp = ei;
  const int* colp = ei + NE;

  float* wsf     = (float*)d_ws;
  float* bn_sums = wsf;                 // 512
  float* EW      = wsf + 1024;          // NE
  float* DINV    = EW + NE;             // NN
  float* BUFA    = DINV + NN;           // NN*64
  float* BUFB    = BUFA + (size_t)NN * 64;      // NN*64
  int*   PTR    = (int*)(BUFB + (size_t)NN * 64);  // NN+1
  int*   FILL   = PTR + (NN + 1);       // NN
  int*   EIDX   = FILL + NN;            // NE
  int*   CNT    = EIDX + NE;            // NN
  int*   BSUM   = CNT + NN;             // 391
  uint32_t* W2T  = (uint32_t*)BUFA;     // 8192 u32 (dead before conv1 gemm)
  float* PRM     = BUFB;                // 896 floats (dead before conv1 agg)

  hipMemsetAsync(bn_sums, 0, 512 * sizeof(float), stream);
  hipMemsetAsync(DINV, 0, NN * sizeof(float), stream);
  hipMemsetAsync(CNT, 0, NN * sizeof(int), stream);

  bn_stats<<<1000, 256, 0, stream>>>(edgenet, pw1, pb1, bn_sums);
  bn_finalize<<<1, 256, 0, stream>>>(bn_sums, pw1, pb1, pgamma, pbeta, PRM);
  w2_prep<<<32, 256, 0, stream>>>(pw2, W2T);

  // CSR build (independent of pae)
  csr_hist<<<(NE + 255) / 256, 256, 0, stream>>>(colp, CNT);
  csr_scanA<<<391, 256, 0, stream>>>(CNT, PTR, BSUM);
  csr_scanB<<<1, 512, 0, stream>>>(BSUM);
  csr_scanAdd<<<391, 256, 0, stream>>>(PTR, BSUM, FILL);
  csr_fill<<<(NE + 255) / 256, 256, 0, stream>>>(colp, FILL, EIDX);

  pae_edge<<<NE / 32, 256, 0, stream>>>(edgenet, PRM, W2T, pb2, colp, EW, DINV);
  deg_to_dinv<<<(NN + 255) / 256, 256, 0, stream>>>(DINV);

  // conv1
  gemm_feat<<<(NN + 63) / 64, 256, 0, stream>>>(x, c1w, BUFA, NN);
  gather_agg<<<(NN + 3) / 4, 256, 0, stream>>>(rowp, PTR, EIDX, EW, DINV, BUFA, c1b, BUFB);

  // conv2
  gemm_feat<<<(NN + 63) / 64, 256, 0, stream>>>(BUFB, c2w, BUFA, NN);
  gather_agg<<<(NN + 3) / 4, 256, 0, stream>>>(rowp, PTR, EIDX, EW, DINV, BUFA, c2b, BUFB);

  // head
  head_kernel<<<NN / 8, 256, 0, stream>>>(BUFB, l1w, l1b, l2w, l2b, out);
}

// Round 5
// 1237.336 us; speedup vs baseline: 1.1325x; 1.1325x over previous
//
#include <hip/hip_runtime.h>
#include <stdint.h>

// ---------------------------------------------------------------------------
// Node_GCN: PAE edge weights (MLP+BN+dropout+cosine) -> 2x GCNConv -> MLP head
// R5: aggregation/GEMM commute => conv = gather(raw feats) + fused 16-node
// mini-GEMM per block. conv2 fuses the entire MLP head (h2 never hits HBM).
// csr_coef packs (row, dinv[row]*ew) per edge in CSR order -> 1 broadcast
// load/edge in convs. deg_to_dinv gone (inline rsqrt). 12 launches total.
// ---------------------------------------------------------------------------

#define NN 100000
#define NE 1000000
#define INV_KEEP (1.0f/0.7f)
// uniform(bits) < 0.7  <=>  bits < 5872026<<9   (0.7f = 0x3F333333 exactly)
#define KEEP_THR 3006477312u

typedef short bf16x8 __attribute__((ext_vector_type(8)));
typedef float f32x4  __attribute__((ext_vector_type(4)));
typedef uint32_t u32x4 __attribute__((ext_vector_type(4)));

// ---- threefry2x32 (20 rounds), exact jax/_src/prng.py semantics -----------
__host__ __device__ constexpr uint32_t rotl32c(uint32_t x, int r) {
  return (x << r) | (x >> (32 - r));
}

struct TFK { uint32_t a, b; };
__host__ __device__ constexpr TFK tf_const(uint32_t k0, uint32_t k1,
                                           uint32_t x0, uint32_t x1) {
  uint32_t k2 = k0 ^ k1 ^ 0x1BD11BDAu;
  x0 += k0; x1 += k1;
#define TFC_R(r) { x0 += x1; x1 = rotl32c(x1, (r)); x1 ^= x0; }
  TFC_R(13) TFC_R(15) TFC_R(26) TFC_R(6)   x0 += k1; x1 += k2 + 1u;
  TFC_R(17) TFC_R(29) TFC_R(16) TFC_R(24)  x0 += k2; x1 += k0 + 2u;
  TFC_R(13) TFC_R(15) TFC_R(26) TFC_R(6)   x0 += k0; x1 += k1 + 3u;
  TFC_R(17) TFC_R(29) TFC_R(16) TFC_R(24)  x0 += k1; x1 += k2 + 4u;
  TFC_R(13) TFC_R(15) TFC_R(26) TFC_R(6)   x0 += k2; x1 += k0 + 5u;
#undef TFC_R
  return TFK{x0, x1};
}

// keys from jax.random.split(jax.random.key(42)), partitionable mode
constexpr TFK KP = tf_const(0u, 42u, 0u, 0u);
constexpr TFK KH = tf_const(0u, 42u, 0u, 1u);

// partitionable random bits for element idx: threefry(key,(0,idx)) -> o0^o1
template <uint32_t K0, uint32_t K1>
__device__ __forceinline__ uint32_t tf_bits(uint32_t idx) {
  constexpr uint32_t K2 = K0 ^ K1 ^ 0x1BD11BDAu;
  uint32_t x0 = K0;
  uint32_t x1 = idx + K1;
#define TF_R(r) { x0 += x1; \
    x1 = __builtin_amdgcn_alignbit(x1, x1, 32u - (r)) ^ x0; }
  TF_R(13) TF_R(15) TF_R(26) TF_R(6)   x0 += K1; x1 += K2 + 1u;
  TF_R(17) TF_R(29) TF_R(16) TF_R(24)  x0 += K2; x1 += K0 + 2u;
  TF_R(13) TF_R(15) TF_R(26) TF_R(6)   x0 += K0; x1 += K1 + 3u;
  TF_R(17) TF_R(29) TF_R(16) TF_R(24)  x0 += K1; x1 += K2 + 4u;
  TF_R(13) TF_R(15) TF_R(26) TF_R(6)   x0 += K2; x1 += K0 + 5u;
#undef TF_R
  return x0 ^ x1;
}

__device__ __forceinline__ uint16_t f2bf(float f) {  // RNE (cold paths only)
  uint32_t u = __float_as_uint(f);
  return (uint16_t)((u + 0x7FFFu + ((u >> 16) & 1u)) >> 16);
}

// ---------------------------------------------------------------------------
// K1: BN stats. thread=(channel c, parity g); each thread reads full float4
// edge rows (wave-uniform broadcast), accumulates both halves.
// sums[s*128+c] = sum h ; sums[256+s*128+c] = sum h^2. 2000 blocks x 500.
// ---------------------------------------------------------------------------
__global__ __launch_bounds__(256) void bn_stats(const float* __restrict__ edgenet,
                                                const float* __restrict__ w1,
                                                const float* __restrict__ b1,
                                                float* __restrict__ sums) {
  int t = threadIdx.x;
  int c = t & 127, g = t >> 7;           // g uniform per wave
  float wA = w1[c], wB = w1[128 + c], bb = b1[c];
  const float4* ed4 = (const float4*)edgenet;
  int e0 = blockIdx.x * 500;
  float s0 = 0.f, q0 = 0.f, s1 = 0.f, q1 = 0.f;
#pragma unroll 4
  for (int e = g; e < 500; e += 2) {
    float4 x = ed4[e0 + e];
    float h = fmaxf(fmaf(x.y, wB, fmaf(x.x, wA, bb)), 0.f);
    s0 += h; q0 = fmaf(h, h, q0);
    h = fmaxf(fmaf(x.w, wB, fmaf(x.z, wA, bb)), 0.f);
    s1 += h; q1 = fmaf(h, h, q1);
  }
  atomicAdd(&sums[c], s0);
  atomicAdd(&sums[256 + c], q0);
  atomicAdd(&sums[128 + c], s1);
  atomicAdd(&sums[384 + c], q1);
}

// ---------------------------------------------------------------------------
// K2: prep = bn_finalize (block 32) + w2->bf16 transpose (blocks 0..31).
// PRM (896 floats): [0]wA [128]wB [256]b1 [384]aK[256] [640]bK[256]
// ---------------------------------------------------------------------------
__global__ void prep(const float* __restrict__ sums,
                     const float* __restrict__ w1,
                     const float* __restrict__ b1,
                     const float* __restrict__ gamma,
                     const float* __restrict__ beta,
                     const float* __restrict__ w2,
                     float* __restrict__ prm,
                     uint32_t* __restrict__ w2t) {
  int t = threadIdx.x;
  if (blockIdx.x < 32) {
    int i = blockIdx.x * 256 + t;        // < 8192, one uint = 2 bf16 along k
    int n = i >> 6, kp = i & 63;
    float f0 = w2[(2 * kp) * 128 + n];
    float f1 = w2[(2 * kp + 1) * 128 + n];
    w2t[i] = (uint32_t)f2bf(f0) | ((uint32_t)f2bf(f1) << 16);
  } else {
    int c = t & 127;
    const float invE = 1.0f / (float)NE;
    float mean = sums[t] * invE;
    float var = fmaxf(sums[256 + t] * invE - mean * mean, 0.f);
    float rstd = rsqrtf(var + 1e-5f);
    float a = gamma[c] * rstd;
    prm[384 + t] = a * INV_KEEP;
    prm[640 + t] = (beta[c] - mean * a) * INV_KEEP;
    if (t < 128) { prm[t] = w1[t]; prm[128 + t] = w1[128 + t]; prm[256 + t] = b1[t]; }
  }
}

// ---------------------------------------------------------------------------
// K3: PAE fused, fragment-direct (unchanged from R4; ~irreducible threefry).
// ---------------------------------------------------------------------------
__global__ __launch_bounds__(256, 3) void pae_edge(const float* __restrict__ edgenet,
                                                const float* __restrict__ prm_g,
                                                const uint32_t* __restrict__ w2t,
                                                const float* __restrict__ b2,
                                                const int* __restrict__ colp,
                                                float* __restrict__ ew_out,
                                                float* __restrict__ deg) {
  __shared__ __align__(16) uint16_t w2s[128 * 136];  // B tile [n][k], +8 pad
  __shared__ __align__(16) float prm[896];
  __shared__ float b2s[128];
  int t = threadIdx.x;
  int e0 = blockIdx.x * 32;
  for (int i = t; i < 8192; i += 256) {               // stage w2t -> LDS
    int n = i >> 6, kp = i & 63;
    *(uint32_t*)&w2s[n * 136 + 2 * kp] = w2t[i];
  }
  for (int i = t; i < 896; i += 256) prm[i] = prm_g[i];
  if (t < 128) b2s[t] = b2[t];
  __syncthreads();

  int lane = t & 63, w = t >> 6;
  int cl = lane & 15, quad = lane >> 4;
  int quad8 = quad * 8;
  int row = 16 * w + cl;
  int el = row >> 1, s = row & 1;
  int so = s << 7;                                    // s*128
  float2 xv = *(const float2*)&edgenet[(size_t)(e0 + el) * 4 + 2 * s];
  uint32_t rowbase = (uint32_t)(e0 + el) * 128u + (s ? 128000000u : 0u);

  f32x4 acc[8];
#pragma unroll
  for (int nt = 0; nt < 8; ++nt) acc[nt] = (f32x4){0.f, 0.f, 0.f, 0.f};

#pragma unroll
  for (int kt = 0; kt < 4; ++kt) {
    int c0 = kt * 32 + quad8;
    uint32_t idxbase = rowbase + (uint32_t)c0;
    float wa[8], wb[8], bb[8], ak[8], bk[8];
    *(float4*)&wa[0] = *(const float4*)&prm[c0];
    *(float4*)&wa[4] = *(const float4*)&prm[c0 + 4];
    *(float4*)&wb[0] = *(const float4*)&prm[128 + c0];
    *(float4*)&wb[4] = *(const float4*)&prm[132 + c0];
    *(float4*)&bb[0] = *(const float4*)&prm[256 + c0];
    *(float4*)&bb[4] = *(const float4*)&prm[260 + c0];
    *(float4*)&ak[0] = *(const float4*)&prm[384 + so + c0];
    *(float4*)&ak[4] = *(const float4*)&prm[388 + so + c0];
    *(float4*)&bk[0] = *(const float4*)&prm[640 + so + c0];
    *(float4*)&bk[4] = *(const float4*)&prm[644 + so + c0];
    uint32_t pk[4];
#pragma unroll
    for (int jp = 0; jp < 4; ++jp) {
      uint32_t u[2];
#pragma unroll
      for (int q = 0; q < 2; ++q) {
        int j = 2 * jp + q;
        float h = fmaxf(fmaf(xv.y, wb[j], fmaf(xv.x, wa[j], bb[j])), 0.f);
        float hn = fmaf(h, ak[j], bk[j]);
        uint32_t bits = tf_bits<KP.a, KP.b>(idxbase + (uint32_t)j);
        float hd = (bits < KEEP_THR) ? hn : 0.f;
        u[q] = __float_as_uint(hd) + 0x8000u;
      }
      pk[jp] = __builtin_amdgcn_perm(u[1], u[0], 0x07060302u);
    }
    u32x4 pkv = {pk[0], pk[1], pk[2], pk[3]};
    bf16x8 afr = __builtin_bit_cast(bf16x8, pkv);
    const uint16_t* bbase = &w2s[(size_t)c0];
#pragma unroll
    for (int nt = 0; nt < 8; ++nt) {
      bf16x8 bfr = *(const bf16x8*)&bbase[(nt * 16 + cl) * 136];
      acc[nt] = __builtin_amdgcn_mfma_f32_16x16x32_bf16(afr, bfr, acc[nt], 0, 0, 0);
    }
  }

  float p11[2] = {0.f, 0.f}, p22[2] = {0.f, 0.f}, p12[2] = {0.f, 0.f};
#pragma unroll
  for (int nt = 0; nt < 8; ++nt) {
    float bv = b2s[nt * 16 + cl];
#pragma unroll
    for (int u = 0; u < 2; ++u) {
      float v1 = acc[nt][2 * u] + bv;
      float v2 = acc[nt][2 * u + 1] + bv;
      p11[u] = fmaf(v1, v1, p11[u]);
      p22[u] = fmaf(v2, v2, p22[u]);
      p12[u] = fmaf(v1, v2, p12[u]);
    }
  }
#pragma unroll
  for (int u = 0; u < 2; ++u) {
    float a = p11[u], b = p22[u], d = p12[u];
    for (int off = 1; off < 16; off <<= 1) {
      a += __shfl_xor(a, off, 64);
      b += __shfl_xor(b, off, 64);
      d += __shfl_xor(d, off, 64);
    }
    if (cl == 0) {
      int e = e0 + 8 * w + 2 * quad + u;
      float n1 = fmaxf(sqrtf(a), 1e-8f);
      float n2 = fmaxf(sqrtf(b), 1e-8f);
      float ew = (d / (n1 * n2) + 1.f) * 0.5f;
      ew_out[e] = ew;
      atomicAdd(&deg[colp[e]], ew);   // fused degree scatter (raw deg)
    }
  }
}

// ---------------------------------------------------------------------------
// CSR build: hist -> 2-level exclusive scan -> fill
// ---------------------------------------------------------------------------
__global__ void csr_hist(const int* __restrict__ col, int* __restrict__ cnt) {
  int e = blockIdx.x * 256 + threadIdx.x;
  if (e < NE) atomicAdd(&cnt[col[e]], 1);
}

__global__ __launch_bounds__(256) void csr_scanA(const int* __restrict__ cnt,
                                                 int* __restrict__ ptr,
                                                 int* __restrict__ bsum) {
  __shared__ int sh[256];
  int t = threadIdx.x;
  int i = blockIdx.x * 256 + t;
  int x = (i < NN) ? cnt[i] : 0;
  sh[t] = x;
  __syncthreads();
  for (int o = 1; o < 256; o <<= 1) {
    int v = (t >= o) ? sh[t - o] : 0;
    __syncthreads();
    sh[t] += v;
    __syncthreads();
  }
  if (i < NN) ptr[i] = sh[t] - x;
  if (t == 255) bsum[blockIdx.x] = sh[255];
}

__global__ __launch_bounds__(512) void csr_scanB(int* __restrict__ bsum) {
  __shared__ int sh[512];
  int t = threadIdx.x;
  int x = (t < 391) ? bsum[t] : 0;
  sh[t] = x;
  __syncthreads();
  for (int o = 1; o < 512; o <<= 1) {
    int v = (t >= o) ? sh[t - o] : 0;
    __syncthreads();
    sh[t] += v;
    __syncthreads();
  }
  if (t < 391) bsum[t] = sh[t] - x;
}

__global__ void csr_scanAdd(int* __restrict__ ptr, const int* __restrict__ bsum,
                            int* __restrict__ fill) {
  int i = blockIdx.x * 256 + threadIdx.x;
  if (i < NN) {
    int v = ptr[i] + bsum[blockIdx.x];
    ptr[i] = v;
    fill[i] = v;
    if (i == NN - 1) ptr[NN] = NE;
  }
}

__global__ void csr_fill(const int* __restrict__ col, int* __restrict__ fill,
                         int* __restrict__ eidx) {
  int e = blockIdx.x * 256 + threadIdx.x;
  if (e < NE) {
    int p = atomicAdd(&fill[col[e]], 1);
    eidx[p] = e;
  }
}

// ---------------------------------------------------------------------------
// K4b: per-edge packed coefficients in CSR order: epk[p] = {row, dinv_r*ew}.
// Runs after pae (deg final). One 8B broadcast load/edge in the convs.
// ---------------------------------------------------------------------------
__global__ void csr_coef(const int* __restrict__ eidx, const int* __restrict__ rowp,
                         const float* __restrict__ ew, const float* __restrict__ deg,
                         int2* __restrict__ epk) {
  int p = blockIdx.x * 256 + threadIdx.x;
  if (p < NE) {
    int e = eidx[p];
    int r = rowp[e];
    float cf = rsqrtf(deg[r] + 1.0f) * ew[e];
    epk[p] = make_int2(r, __float_as_int(cf));
  }
}

// ---------------------------------------------------------------------------
// K6: conv1 fused = CSR gather on raw features + 16-node mini-GEMM + b + relu.
// Block: 256 thr, 16 nodes. Wave w gathers nodes 4w..4w+3 (lane=channel).
// t[v] = dinv_v * sum_e cf_e * x[r_e] + dinv_v^2 * x[v]  -> LDS T[16][68]
// then out[n][c'] = relu(sum_k T[n][k] W[k][c'] + bias[c']).
// ---------------------------------------------------------------------------
__global__ __launch_bounds__(256) void conv1_fused(const int* __restrict__ ptr,
                                                   const int2* __restrict__ epk,
                                                   const float* __restrict__ deg,
                                                   const float* __restrict__ x,
                                                   const float* __restrict__ W,
                                                   const float* __restrict__ bias,
                                                   float* __restrict__ out) {
  __shared__ __align__(16) float Ws[4096];   // [k][c'] 16KB
  __shared__ __align__(16) float T[16 * 68];
  __shared__ float biass[64];
  int t = threadIdx.x;
  for (int i = t; i < 4096; i += 256) Ws[i] = W[i];
  if (t < 64) biass[t] = bias[t];
  int w = t >> 6, c = t & 63;
  int v0 = blockIdx.x * 16;
#pragma unroll 1
  for (int i = 0; i < 4; ++i) {
    int n = 4 * w + i;
    int v = v0 + n;
    int p = ptr[v], end = ptr[v + 1];
    float acc = 0.f;
    int r = 0; float cf = 0.f;
    if (p < end) { int2 pk = epk[p]; r = pk.x; cf = __int_as_float(pk.y); }
    while (p < end) {
      int r0 = r; float cf0 = cf;
      ++p;
      if (p < end) { int2 pk = epk[p]; r = pk.x; cf = __int_as_float(pk.y); }
      acc = fmaf(cf0, x[(size_t)r0 * 64 + c], acc);
    }
    float dv = rsqrtf(deg[v] + 1.0f);
    T[n * 68 + c] = fmaf(dv, acc, dv * dv * x[(size_t)v * 64 + c]);
  }
  __syncthreads();
  int n = t >> 4, cq = (t & 15) * 4;
  float4 o = *(const float4*)&biass[cq];
#pragma unroll 4
  for (int k = 0; k < 64; ++k) {
    float a = T[n * 68 + k];
    float4 wv = *(const float4*)&Ws[k * 64 + cq];
    o.x = fmaf(a, wv.x, o.x);
    o.y = fmaf(a, wv.y, o.y);
    o.z = fmaf(a, wv.z, o.z);
    o.w = fmaf(a, wv.w, o.w);
  }
  o.x = fmaxf(o.x, 0.f); o.y = fmaxf(o.y, 0.f);
  o.z = fmaxf(o.z, 0.f); o.w = fmaxf(o.w, 0.f);
  *(float4*)&out[(size_t)(v0 + n) * 64 + cq] = o;
}

// ---------------------------------------------------------------------------
// K7: conv2 + full MLP head fused. Same gather+GEMM as conv1 -> h2 in LDS,
// then per-node GEMV(L1)+relu+dropout(k_head)+GEMV(L2) -> out[10].
// ---------------------------------------------------------------------------
__global__ __launch_bounds__(256) void conv2_head(const int* __restrict__ ptr,
                                                  const int2* __restrict__ epk,
                                                  const float* __restrict__ deg,
                                                  const float* __restrict__ h1,
                                                  const float* __restrict__ W,
                                                  const float* __restrict__ bias,
                                                  const float* __restrict__ l1w,
                                                  const float* __restrict__ l1b,
                                                  const float* __restrict__ l2w,
                                                  const float* __restrict__ l2b,
                                                  float* __restrict__ out) {
  __shared__ __align__(16) float Ws[4096];     // c2w [k][c']
  __shared__ __align__(16) float T[16 * 68];   // gather out, later reused as M
  __shared__ __align__(16) float H2[16 * 68];
  __shared__ float L1s[64 * 33];               // [k][j]
  __shared__ float L2s[320];                   // [j][f]
  __shared__ float biass[64], l1bs[32], l2bs[16];
  int t = threadIdx.x;
  for (int i = t; i < 4096; i += 256) Ws[i] = W[i];
  for (int i = t; i < 2048; i += 256) {
    int k = i >> 5, j = i & 31;
    L1s[k * 33 + j] = l1w[i];
  }
  for (int i = t; i < 320; i += 256) L2s[i] = l2w[i];
  if (t < 64) biass[t] = bias[t];
  if (t < 32) l1bs[t] = l1b[t];
  if (t < 10) l2bs[t] = l2b[t];
  int w = t >> 6, c = t & 63;
  int v0 = blockIdx.x * 16;
#pragma unroll 1
  for (int i = 0; i < 4; ++i) {
    int n = 4 * w + i;
    int v = v0 + n;
    int p = ptr[v], end = ptr[v + 1];
    float acc = 0.f;
    int r = 0; float cf = 0.f;
    if (p < end) { int2 pk = epk[p]; r = pk.x; cf = __int_as_float(pk.y); }
    while (p < end) {
      int r0 = r; float cf0 = cf;
      ++p;
      if (p < end) { int2 pk = epk[p]; r = pk.x; cf = __int_as_float(pk.y); }
      acc = fmaf(cf0, h1[(size_t)r0 * 64 + c], acc);
    }
    float dv = rsqrtf(deg[v] + 1.0f);
    T[n * 68 + c] = fmaf(dv, acc, dv * dv * h1[(size_t)v * 64 + c]);
  }
  __syncthreads();
  // mini-GEMM: h2 = relu(T @ c2w + b)
  {
    int n = t >> 4, cq = (t & 15) * 4;
    float4 o = *(const float4*)&biass[cq];
#pragma unroll 4
    for (int k = 0; k < 64; ++k) {
      float a = T[n * 68 + k];
      float4 wv = *(const float4*)&Ws[k * 64 + cq];
      o.x = fmaf(a, wv.x, o.x);
      o.y = fmaf(a, wv.y, o.y);
      o.z = fmaf(a, wv.z, o.z);
      o.w = fmaf(a, wv.w, o.w);
    }
    o.x = fmaxf(o.x, 0.f); o.y = fmaxf(o.y, 0.f);
    o.z = fmaxf(o.z, 0.f); o.w = fmaxf(o.w, 0.f);
    __syncthreads();                 // T fully read by all before overwrite
    *(float4*)&H2[n * 68 + cq] = o;
  }
  __syncthreads();
  // head hidden: M[n][j] = dropout(relu(H2[n]. L1[:,j] + b))  (T reused as M)
  {
    int n = t >> 4, j0 = t & 15;
#pragma unroll
    for (int jj = 0; jj < 2; ++jj) {
      int j = j0 + 16 * jj;
      float m = l1bs[j];
#pragma unroll 4
      for (int k = 0; k < 64; ++k) m = fmaf(H2[n * 68 + k], L1s[k * 33 + j], m);
      m = fmaxf(m, 0.f);
      uint32_t idx = (uint32_t)(v0 + n) * 32u + (uint32_t)j;
      bool kp = tf_bits<KH.a, KH.b>(idx) < KEEP_THR;
      T[n * 33 + j] = kp ? m * INV_KEEP : 0.f;
    }
  }
  __syncthreads();
  // out: 16 nodes x 10 classes
  if (t < 160) {
    int n = t / 10, f = t % 10;
    float s = l2bs[f];
#pragma unroll
    for (int j = 0; j < 32; ++j) s = fmaf(T[n * 33 + j], L2s[j * 10 + f], s);
    out[(size_t)(v0 + n) * 10 + f] = s;
  }
}

// ---------------------------------------------------------------------------
extern "C" void kernel_launch(void* const* d_in, const int* in_sizes, int n_in,
                              void* d_out, int out_size, void* d_ws, size_t ws_size,
                              hipStream_t stream) {
  const float* x       = (const float*)d_in[0];
  const int*   ei      = (const int*)d_in[1];
  const float* edgenet = (const float*)d_in[2];
  const float* pw1     = (const float*)d_in[3];
  const float* pb1     = (const float*)d_in[4];
  const float* pgamma  = (const float*)d_in[5];
  const float* pbeta   = (const float*)d_in[6];
  const float* pw2     = (const float*)d_in[7];
  const float* pb2     = (const float*)d_in[8];
  const float* c1w     = (const float*)d_in[9];
  const float* c1b     = (const float*)d_in[10];
  const float* c2w     = (const float*)d_in[11];
  const float* c2b     = (const float*)d_in[12];
  const float* l1w     = (const float*)d_in[13];
  const float* l1b     = (const float*)d_in[14];
  const float* l2w     = (const float*)d_in[15];
  const float* l2b     = (const float*)d_in[16];
  float* out = (float*)d_out;

  const int* rowp = ei;
  const int* colp = ei + NE;

  // workspace layout (one contiguous zero region first: bn_sums, DEG, CNT)
  float* wsf     = (float*)d_ws;
  float* bn_sums = wsf;                           // 512
  float* DEG     = wsf + 512;                     // NN
  int*   CNT     = (int*)(wsf + 512 + NN);        // NN
  float* EW      = wsf + 512 + 2 * NN;            // NE
  int*   PTR     = (int*)(EW + NE);               // NN+1
  int*   FILL    = PTR + NN + 1;                  // NN
  int*   EIDX    = FILL + NN;                     // NE
  int2*  EPK     = (int2*)(EIDX + NE);            // NE int2
  float* H1      = (float*)(EPK + NE);            // NN*64
  int*   BSUM    = (int*)(H1 + (size_t)NN * 64);  // 391 (pad 512)
  uint32_t* W2T  = (uint32_t*)(BSUM + 512);       // 8192
  float* PRM     = (float*)(W2T + 8192);          // 896

  hipMemsetAsync(bn_sums, 0, (512 + 2 * NN) * sizeof(float), stream);

  bn_stats<<<2000, 256, 0, stream>>>(edgenet, pw1, pb1, bn_sums);
  prep<<<33, 256, 0, stream>>>(bn_sums, pw1, pb1, pgamma, pbeta, pw2, PRM, W2T);

  // CSR build (independent of pae)
  csr_hist<<<(NE + 255) / 256, 256, 0, stream>>>(colp, CNT);
  csr_scanA<<<391, 256, 0, stream>>>(CNT, PTR, BSUM);
  csr_scanB<<<1, 512, 0, stream>>>(BSUM);
  csr_scanAdd<<<391, 256, 0, stream>>>(PTR, BSUM, FILL);
  csr_fill<<<(NE + 255) / 256, 256, 0, stream>>>(colp, FILL, EIDX);

  pae_edge<<<NE / 32, 256, 0, stream>>>(edgenet, PRM, W2T, pb2, colp, EW, DEG);
  csr_coef<<<(NE + 255) / 256, 256, 0, stream>>>(EIDX, rowp, EW, DEG, EPK);

  conv1_fused<<<NN / 16, 256, 0, stream>>>(PTR, EPK, DEG, x, c1w, c1b, H1);
  conv2_head<<<NN / 16, 256, 0, stream>>>(PTR, EPK, DEG, H1, c2w, c2b,
                                          l1w, l1b, l2w, l2b, out);
}

// Round 6
// 1221.164 us; speedup vs baseline: 1.1475x; 1.0132x over previous
//
#include <hip/hip_runtime.h>
#include <stdint.h>

// ---------------------------------------------------------------------------
// Node_GCN: PAE edge weights (MLP+BN+dropout+cosine) -> 2x GCNConv -> MLP head
// R6: dropout keep-bits precomputed into a 32MB bitmask by a minimal
// grid-stride threefry kernel, co-dispatched with bn_stats + csr_hist
// (phase1). pae_edge applies the mask via v_bfe_i32+v_and (2 ops/elem).
// csr_fill+w2_prep+bn_finalize merged (phase2). 10 launches, ws 45.6 MB.
// MSK aliases H1 (dead before conv1 writes H1).
// ---------------------------------------------------------------------------

#define NN 100000
#define NE 1000000
#define INV_KEEP (1.0f/0.7f)
// uniform(bits) < 0.7  <=>  bits < 5872026<<9   (0.7f = 0x3F333333 exactly)
#define KEEP_THR 3006477312u

#define HIST_BLOCKS 3907
#define BN_BLOCKS   1000
#define MASK_WORDS  8000000   // NE * 2 halves * 4 kt-words(32b)

typedef short bf16x8 __attribute__((ext_vector_type(8)));
typedef float f32x4  __attribute__((ext_vector_type(4)));
typedef uint32_t u32x4 __attribute__((ext_vector_type(4)));

// ---- threefry2x32 (20 rounds), exact jax/_src/prng.py semantics -----------
__host__ __device__ constexpr uint32_t rotl32c(uint32_t x, int r) {
  return (x << r) | (x >> (32 - r));
}

struct TFK { uint32_t a, b; };
__host__ __device__ constexpr TFK tf_const(uint32_t k0, uint32_t k1,
                                           uint32_t x0, uint32_t x1) {
  uint32_t k2 = k0 ^ k1 ^ 0x1BD11BDAu;
  x0 += k0; x1 += k1;
#define TFC_R(r) { x0 += x1; x1 = rotl32c(x1, (r)); x1 ^= x0; }
  TFC_R(13) TFC_R(15) TFC_R(26) TFC_R(6)   x0 += k1; x1 += k2 + 1u;
  TFC_R(17) TFC_R(29) TFC_R(16) TFC_R(24)  x0 += k2; x1 += k0 + 2u;
  TFC_R(13) TFC_R(15) TFC_R(26) TFC_R(6)   x0 += k0; x1 += k1 + 3u;
  TFC_R(17) TFC_R(29) TFC_R(16) TFC_R(24)  x0 += k1; x1 += k2 + 4u;
  TFC_R(13) TFC_R(15) TFC_R(26) TFC_R(6)   x0 += k2; x1 += k0 + 5u;
#undef TFC_R
  return TFK{x0, x1};
}

// keys from jax.random.split(jax.random.key(42)), partitionable mode
constexpr TFK KP = tf_const(0u, 42u, 0u, 0u);
constexpr TFK KH = tf_const(0u, 42u, 0u, 1u);

// partitionable random bits for element idx: threefry(key,(0,idx)) -> o0^o1
template <uint32_t K0, uint32_t K1>
__device__ __forceinline__ uint32_t tf_bits(uint32_t idx) {
  constexpr uint32_t K2 = K0 ^ K1 ^ 0x1BD11BDAu;
  uint32_t x0 = K0;
  uint32_t x1 = idx + K1;
#define TF_R(r) { x0 += x1; \
    x1 = __builtin_amdgcn_alignbit(x1, x1, 32u - (r)) ^ x0; }
  TF_R(13) TF_R(15) TF_R(26) TF_R(6)   x0 += K1; x1 += K2 + 1u;
  TF_R(17) TF_R(29) TF_R(16) TF_R(24)  x0 += K2; x1 += K0 + 2u;
  TF_R(13) TF_R(15) TF_R(26) TF_R(6)   x0 += K0; x1 += K1 + 3u;
  TF_R(17) TF_R(29) TF_R(16) TF_R(24)  x0 += K1; x1 += K2 + 4u;
  TF_R(13) TF_R(15) TF_R(26) TF_R(6)   x0 += K2; x1 += K0 + 5u;
#undef TF_R
  return x0 ^ x1;
}

__device__ __forceinline__ uint16_t f2bf(float f) {  // RNE (cold paths only)
  uint32_t u = __float_as_uint(f);
  return (uint16_t)((u + 0x7FFFu + ((u >> 16) & 1u)) >> 16);
}

// ---------------------------------------------------------------------------
// phase1 = bn_stats (blocks 0..999) + csr_hist (1000..4906)
//        + dropout mask gen (4907..36156). Memory-bound blocks first so the
//        VALU-bound mask blocks co-schedule on the remaining capacity.
// Mask word widx: e=widx>>3, s=(widx>>2)&1, kt=widx&3; bit j' (0..31) is
// dropout element idx = e*128 + kt*32 + j' + s*128e6.
// ---------------------------------------------------------------------------
__global__ __launch_bounds__(256) void phase1(const float* __restrict__ edgenet,
                                              const float* __restrict__ w1,
                                              const float* __restrict__ b1,
                                              const int* __restrict__ colp,
                                              float* __restrict__ sums,
                                              int* __restrict__ cnt,
                                              uint32_t* __restrict__ msk) {
  int b = blockIdx.x;
  int t = threadIdx.x;
  if (b < BN_BLOCKS) {
    int c = t & 127, g = t >> 7;
    float wA = w1[c], wB = w1[128 + c], bb = b1[c];
    const float4* ed4 = (const float4*)edgenet;
    int e0 = b * 1000;
    float s0 = 0.f, q0 = 0.f, s1 = 0.f, q1 = 0.f;
#pragma unroll 4
    for (int e = g; e < 1000; e += 2) {
      float4 x = ed4[e0 + e];
      float h = fmaxf(fmaf(x.y, wB, fmaf(x.x, wA, bb)), 0.f);
      s0 += h; q0 = fmaf(h, h, q0);
      h = fmaxf(fmaf(x.w, wB, fmaf(x.z, wA, bb)), 0.f);
      s1 += h; q1 = fmaf(h, h, q1);
    }
    atomicAdd(&sums[c], s0);
    atomicAdd(&sums[256 + c], q0);
    atomicAdd(&sums[128 + c], s1);
    atomicAdd(&sums[384 + c], q1);
  } else if (b < BN_BLOCKS + HIST_BLOCKS) {
    int e = (b - BN_BLOCKS) * 256 + t;
    if (e < NE) atomicAdd(&cnt[colp[e]], 1);
  } else {
    uint32_t widx = (uint32_t)(b - (BN_BLOCKS + HIST_BLOCKS)) * 256u + (uint32_t)t;
    uint32_t e = widx >> 3, sh = (widx >> 2) & 1u, kt = widx & 3u;
    uint32_t base = e * 128u + kt * 32u + (sh ? 128000000u : 0u);
    uint32_t word = 0u;
#pragma unroll 8
    for (int j = 0; j < 32; ++j) {
      uint32_t bits = tf_bits<KP.a, KP.b>(base + (uint32_t)j);
      word |= (bits < KEEP_THR ? 1u : 0u) << j;
    }
    msk[widx] = word;
  }
}

// ---------------------------------------------------------------------------
// CSR scan chain (3 small kernels)
// ---------------------------------------------------------------------------
__global__ __launch_bounds__(256) void csr_scanA(const int* __restrict__ cnt,
                                                 int* __restrict__ ptr,
                                                 int* __restrict__ bsum) {
  __shared__ int sh[256];
  int t = threadIdx.x;
  int i = blockIdx.x * 256 + t;
  int x = (i < NN) ? cnt[i] : 0;
  sh[t] = x;
  __syncthreads();
  for (int o = 1; o < 256; o <<= 1) {
    int v = (t >= o) ? sh[t - o] : 0;
    __syncthreads();
    sh[t] += v;
    __syncthreads();
  }
  if (i < NN) ptr[i] = sh[t] - x;
  if (t == 255) bsum[blockIdx.x] = sh[255];
}

__global__ __launch_bounds__(512) void csr_scanB(int* __restrict__ bsum) {
  __shared__ int sh[512];
  int t = threadIdx.x;
  int x = (t < 391) ? bsum[t] : 0;
  sh[t] = x;
  __syncthreads();
  for (int o = 1; o < 512; o <<= 1) {
    int v = (t >= o) ? sh[t - o] : 0;
    __syncthreads();
    sh[t] += v;
    __syncthreads();
  }
  if (t < 391) bsum[t] = sh[t] - x;
}

__global__ void csr_scanAdd(int* __restrict__ ptr, const int* __restrict__ bsum,
                            int* __restrict__ fill) {
  int i = blockIdx.x * 256 + threadIdx.x;
  if (i < NN) {
    int v = ptr[i] + bsum[blockIdx.x];
    ptr[i] = v;
    fill[i] = v;
    if (i == NN - 1) ptr[NN] = NE;
  }
}

// ---------------------------------------------------------------------------
// phase2 = csr_fill (blocks 0..3906, writes EPK=(row,e))
//        + w2->bf16 transpose (3907..3938) + bn_finalize (3939)
// PRM (896 floats): [0]wA [128]wB [256]b1 [384]aK[256] [640]bK[256]
// ---------------------------------------------------------------------------
__global__ void phase2(const int* __restrict__ rowp, const int* __restrict__ colp,
                       int* __restrict__ fill, int2* __restrict__ epk,
                       const float* __restrict__ sums,
                       const float* __restrict__ w1, const float* __restrict__ b1,
                       const float* __restrict__ gamma, const float* __restrict__ beta,
                       const float* __restrict__ w2,
                       float* __restrict__ prm, uint32_t* __restrict__ w2t) {
  int b = blockIdx.x;
  int t = threadIdx.x;
  if (b < HIST_BLOCKS) {
    int e = b * 256 + t;
    if (e < NE) {
      int r = rowp[e];
      int p = atomicAdd(&fill[colp[e]], 1);
      epk[p] = make_int2(r, e);
    }
  } else if (b < HIST_BLOCKS + 32) {
    int i = (b - HIST_BLOCKS) * 256 + t;   // < 8192
    int n = i >> 6, kp = i & 63;
    float f0 = w2[(2 * kp) * 128 + n];
    float f1 = w2[(2 * kp + 1) * 128 + n];
    w2t[i] = (uint32_t)f2bf(f0) | ((uint32_t)f2bf(f1) << 16);
  } else {
    int c = t & 127;
    const float invE = 1.0f / (float)NE;
    float mean = sums[t] * invE;
    float var = fmaxf(sums[256 + t] * invE - mean * mean, 0.f);
    float rstd = rsqrtf(var + 1e-5f);
    float a = gamma[c] * rstd;
    prm[384 + t] = a * INV_KEEP;
    prm[640 + t] = (beta[c] - mean * a) * INV_KEEP;
    if (t < 128) { prm[t] = w1[t]; prm[128 + t] = w1[128 + t]; prm[256 + t] = b1[t]; }
  }
}

// ---------------------------------------------------------------------------
// K3: PAE fused, fragment-direct; dropout from precomputed bitmask.
// Lane (cl,quad): row=16w+cl, channels c = kt*32+quad*8+j into A fragment.
// mask: word MSK[el*8+s*4+kt], bit (quad*8+j) -> v_bfe_i32 sign-extend + and.
// ---------------------------------------------------------------------------
__global__ __launch_bounds__(256, 3) void pae_edge(const float* __restrict__ edgenet,
                                                const float* __restrict__ prm_g,
                                                const uint32_t* __restrict__ w2t,
                                                const float* __restrict__ b2,
                                                const int* __restrict__ colp,
                                                const uint32_t* __restrict__ msk,
                                                float* __restrict__ ew_out,
                                                float* __restrict__ deg) {
  __shared__ __align__(16) uint16_t w2s[128 * 136];  // B tile [n][k], +8 pad
  __shared__ __align__(16) float prm[896];
  __shared__ float b2s[128];
  int t = threadIdx.x;
  int e0 = blockIdx.x * 32;
  for (int i = t; i < 8192; i += 256) {               // stage w2t -> LDS
    int n = i >> 6, kp = i & 63;
    *(uint32_t*)&w2s[n * 136 + 2 * kp] = w2t[i];
  }
  for (int i = t; i < 896; i += 256) prm[i] = prm_g[i];
  if (t < 128) b2s[t] = b2[t];
  __syncthreads();

  int lane = t & 63, w = t >> 6;
  int cl = lane & 15, quad = lane >> 4;
  int quad8 = quad * 8;
  int row = 16 * w + cl;
  int el = row >> 1, s = row & 1;
  int so = s << 7;                                    // s*128
  float2 xv = *(const float2*)&edgenet[(size_t)(e0 + el) * 4 + 2 * s];
  const uint32_t* mrow = &msk[(size_t)(e0 + el) * 8 + s * 4];

  f32x4 acc[8];
#pragma unroll
  for (int nt = 0; nt < 8; ++nt) acc[nt] = (f32x4){0.f, 0.f, 0.f, 0.f};

#pragma unroll
  for (int kt = 0; kt < 4; ++kt) {
    int c0 = kt * 32 + quad8;
    uint32_t word = mrow[kt];
    float wa[8], wb[8], bb[8], ak[8], bk[8];
    *(float4*)&wa[0] = *(const float4*)&prm[c0];
    *(float4*)&wa[4] = *(const float4*)&prm[c0 + 4];
    *(float4*)&wb[0] = *(const float4*)&prm[128 + c0];
    *(float4*)&wb[4] = *(const float4*)&prm[132 + c0];
    *(float4*)&bb[0] = *(const float4*)&prm[256 + c0];
    *(float4*)&bb[4] = *(const float4*)&prm[260 + c0];
    *(float4*)&ak[0] = *(const float4*)&prm[384 + so + c0];
    *(float4*)&ak[4] = *(const float4*)&prm[388 + so + c0];
    *(float4*)&bk[0] = *(const float4*)&prm[640 + so + c0];
    *(float4*)&bk[4] = *(const float4*)&prm[644 + so + c0];
    uint32_t pk[4];
#pragma unroll
    for (int jp = 0; jp < 4; ++jp) {
      uint32_t u[2];
#pragma unroll
      for (int q = 0; q < 2; ++q) {
        int j = 2 * jp + q;
        float h = fmaxf(fmaf(xv.y, wb[j], fmaf(xv.x, wa[j], bb[j])), 0.f);
        float hn = fmaf(h, ak[j], bk[j]);
        // 1-bit sign-extended field -> 0x0 or 0xFFFFFFFF; AND keeps/zeroes hn
        uint32_t m = (uint32_t)__builtin_amdgcn_sbfe((int)word, quad8 + j, 1);
        u[q] = (__float_as_uint(hn) & m) + 0x8000u;
      }
      pk[jp] = __builtin_amdgcn_perm(u[1], u[0], 0x07060302u);
    }
    u32x4 pkv = {pk[0], pk[1], pk[2], pk[3]};
    bf16x8 afr = __builtin_bit_cast(bf16x8, pkv);
    const uint16_t* bbase = &w2s[(size_t)c0];
#pragma unroll
    for (int nt = 0; nt < 8; ++nt) {
      bf16x8 bfr = *(const bf16x8*)&bbase[(nt * 16 + cl) * 136];
      acc[nt] = __builtin_amdgcn_mfma_f32_16x16x32_bf16(afr, bfr, acc[nt], 0, 0, 0);
    }
  }

  float p11[2] = {0.f, 0.f}, p22[2] = {0.f, 0.f}, p12[2] = {0.f, 0.f};
#pragma unroll
  for (int nt = 0; nt < 8; ++nt) {
    float bv = b2s[nt * 16 + cl];
#pragma unroll
    for (int u = 0; u < 2; ++u) {
      float v1 = acc[nt][2 * u] + bv;
      float v2 = acc[nt][2 * u + 1] + bv;
      p11[u] = fmaf(v1, v1, p11[u]);
      p22[u] = fmaf(v2, v2, p22[u]);
      p12[u] = fmaf(v1, v2, p12[u]);
    }
  }
#pragma unroll
  for (int u = 0; u < 2; ++u) {
    float a = p11[u], b = p22[u], d = p12[u];
    for (int off = 1; off < 16; off <<= 1) {
      a += __shfl_xor(a, off, 64);
      b += __shfl_xor(b, off, 64);
      d += __shfl_xor(d, off, 64);
    }
    if (cl == 0) {
      int e = e0 + 8 * w + 2 * quad + u;
      float n1 = fmaxf(sqrtf(a), 1e-8f);
      float n2 = fmaxf(sqrtf(b), 1e-8f);
      float ew = (d / (n1 * n2) + 1.f) * 0.5f;
      ew_out[e] = ew;
      atomicAdd(&deg[colp[e]], ew);   // fused degree scatter (raw deg)
    }
  }
}

// ---------------------------------------------------------------------------
// csr_coef: EPK[p]=(r,e) -> (r, dinv_r*ew[e]) in place (deg final after pae).
// ---------------------------------------------------------------------------
__global__ void csr_coef(int2* __restrict__ epk, const float* __restrict__ ew,
                         const float* __restrict__ deg) {
  int p = blockIdx.x * 256 + threadIdx.x;
  if (p < NE) {
    int2 pk = epk[p];
    float cf = rsqrtf(deg[pk.x] + 1.0f) * ew[pk.y];
    epk[p] = make_int2(pk.x, __float_as_int(cf));
  }
}

// ---------------------------------------------------------------------------
// conv1 fused = CSR gather on raw features + 16-node mini-GEMM + b + relu.
// ---------------------------------------------------------------------------
__global__ __launch_bounds__(256) void conv1_fused(const int* __restrict__ ptr,
                                                   const int2* __restrict__ epk,
                                                   const float* __restrict__ deg,
                                                   const float* __restrict__ x,
                                                   const float* __restrict__ W,
                                                   const float* __restrict__ bias,
                                                   float* __restrict__ out) {
  __shared__ __align__(16) float Ws[4096];   // [k][c'] 16KB
  __shared__ __align__(16) float T[16 * 68];
  __shared__ float biass[64];
  int t = threadIdx.x;
  for (int i = t; i < 4096; i += 256) Ws[i] = W[i];
  if (t < 64) biass[t] = bias[t];
  int w = t >> 6, c = t & 63;
  int v0 = blockIdx.x * 16;
#pragma unroll 1
  for (int i = 0; i < 4; ++i) {
    int n = 4 * w + i;
    int v = v0 + n;
    int p = ptr[v], end = ptr[v + 1];
    float acc = 0.f;
    int r = 0; float cf = 0.f;
    if (p < end) { int2 pk = epk[p]; r = pk.x; cf = __int_as_float(pk.y); }
    while (p < end) {
      int r0 = r; float cf0 = cf;
      ++p;
      if (p < end) { int2 pk = epk[p]; r = pk.x; cf = __int_as_float(pk.y); }
      acc = fmaf(cf0, x[(size_t)r0 * 64 + c], acc);
    }
    float dv = rsqrtf(deg[v] + 1.0f);
    T[n * 68 + c] = fmaf(dv, acc, dv * dv * x[(size_t)v * 64 + c]);
  }
  __syncthreads();
  int n = t >> 4, cq = (t & 15) * 4;
  float4 o = *(const float4*)&biass[cq];
#pragma unroll 4
  for (int k = 0; k < 64; ++k) {
    float a = T[n * 68 + k];
    float4 wv = *(const float4*)&Ws[k * 64 + cq];
    o.x = fmaf(a, wv.x, o.x);
    o.y = fmaf(a, wv.y, o.y);
    o.z = fmaf(a, wv.z, o.z);
    o.w = fmaf(a, wv.w, o.w);
  }
  o.x = fmaxf(o.x, 0.f); o.y = fmaxf(o.y, 0.f);
  o.z = fmaxf(o.z, 0.f); o.w = fmaxf(o.w, 0.f);
  *(float4*)&out[(size_t)(v0 + n) * 64 + cq] = o;
}

// ---------------------------------------------------------------------------
// conv2 + full MLP head fused.
// ---------------------------------------------------------------------------
__global__ __launch_bounds__(256) void conv2_head(const int* __restrict__ ptr,
                                                  const int2* __restrict__ epk,
                                                  const float* __restrict__ deg,
                                                  const float* __restrict__ h1,
                                                  const float* __restrict__ W,
                                                  const float* __restrict__ bias,
                                                  const float* __restrict__ l1w,
                                                  const float* __restrict__ l1b,
                                                  const float* __restrict__ l2w,
                                                  const float* __restrict__ l2b,
                                                  float* __restrict__ out) {
  __shared__ __align__(16) float Ws[4096];     // c2w [k][c']
  __shared__ __align__(16) float T[16 * 68];   // gather out, later reused as M
  __shared__ __align__(16) float H2[16 * 68];
  __shared__ float L1s[64 * 33];               // [k][j]
  __shared__ float L2s[320];                   // [j][f]
  __shared__ float biass[64], l1bs[32], l2bs[16];
  int t = threadIdx.x;
  for (int i = t; i < 4096; i += 256) Ws[i] = W[i];
  for (int i = t; i < 2048; i += 256) {
    int k = i >> 5, j = i & 31;
    L1s[k * 33 + j] = l1w[i];
  }
  for (int i = t; i < 320; i += 256) L2s[i] = l2w[i];
  if (t < 64) biass[t] = bias[t];
  if (t < 32) l1bs[t] = l1b[t];
  if (t < 10) l2bs[t] = l2b[t];
  int w = t >> 6, c = t & 63;
  int v0 = blockIdx.x * 16;
#pragma unroll 1
  for (int i = 0; i < 4; ++i) {
    int n = 4 * w + i;
    int v = v0 + n;
    int p = ptr[v], end = ptr[v + 1];
    float acc = 0.f;
    int r = 0; float cf = 0.f;
    if (p < end) { int2 pk = epk[p]; r = pk.x; cf = __int_as_float(pk.y); }
    while (p < end) {
      int r0 = r; float cf0 = cf;
      ++p;
      if (p < end) { int2 pk = epk[p]; r = pk.x; cf = __int_as_float(pk.y); }
      acc = fmaf(cf0, h1[(size_t)r0 * 64 + c], acc);
    }
    float dv = rsqrtf(deg[v] + 1.0f);
    T[n * 68 + c] = fmaf(dv, acc, dv * dv * h1[(size_t)v * 64 + c]);
  }
  __syncthreads();
  {
    int n = t >> 4, cq = (t & 15) * 4;
    float4 o = *(const float4*)&biass[cq];
#pragma unroll 4
    for (int k = 0; k < 64; ++k) {
      float a = T[n * 68 + k];
      float4 wv = *(const float4*)&Ws[k * 64 + cq];
      o.x = fmaf(a, wv.x, o.x);
      o.y = fmaf(a, wv.y, o.y);
      o.z = fmaf(a, wv.z, o.z);
      o.w = fmaf(a, wv.w, o.w);
    }
    o.x = fmaxf(o.x, 0.f); o.y = fmaxf(o.y, 0.f);
    o.z = fmaxf(o.z, 0.f); o.w = fmaxf(o.w, 0.f);
    __syncthreads();
    *(float4*)&H2[n * 68 + cq] = o;
  }
  __syncthreads();
  {
    int n = t >> 4, j0 = t & 15;
#pragma unroll
    for (int jj = 0; jj < 2; ++jj) {
      int j = j0 + 16 * jj;
      float m = l1bs[j];
#pragma unroll 4
      for (int k = 0; k < 64; ++k) m = fmaf(H2[n * 68 + k], L1s[k * 33 + j], m);
      m = fmaxf(m, 0.f);
      uint32_t idx = (uint32_t)(v0 + n) * 32u + (uint32_t)j;
      bool kp = tf_bits<KH.a, KH.b>(idx) < KEEP_THR;
      T[n * 33 + j] = kp ? m * INV_KEEP : 0.f;
    }
  }
  __syncthreads();
  if (t < 160) {
    int n = t / 10, f = t % 10;
    float s = l2bs[f];
#pragma unroll
    for (int j = 0; j < 32; ++j) s = fmaf(T[n * 33 + j], L2s[j * 10 + f], s);
    out[(size_t)(v0 + n) * 10 + f] = s;
  }
}

// ---------------------------------------------------------------------------
extern "C" void kernel_launch(void* const* d_in, const int* in_sizes, int n_in,
                              void* d_out, int out_size, void* d_ws, size_t ws_size,
                              hipStream_t stream) {
  const float* x       = (const float*)d_in[0];
  const int*   ei      = (const int*)d_in[1];
  const float* edgenet = (const float*)d_in[2];
  const float* pw1     = (const float*)d_in[3];
  const float* pb1     = (const float*)d_in[4];
  const float* pgamma  = (const float*)d_in[5];
  const float* pbeta   = (const float*)d_in[6];
  const float* pw2     = (const float*)d_in[7];
  const float* pb2     = (const float*)d_in[8];
  const float* c1w     = (const float*)d_in[9];
  const float* c1b     = (const float*)d_in[10];
  const float* c2w     = (const float*)d_in[11];
  const float* c2b     = (const float*)d_in[12];
  const float* l1w     = (const float*)d_in[13];
  const float* l1b     = (const float*)d_in[14];
  const float* l2w     = (const float*)d_in[15];
  const float* l2b     = (const float*)d_in[16];
  float* out = (float*)d_out;

  const int* rowp = ei;
  const int* colp = ei + NE;

  // workspace layout (word units); zero region [bn_sums, DEG, CNT] contiguous
  float* wsf     = (float*)d_ws;
  float* bn_sums = wsf;                             // 512
  float* DEG     = wsf + 512;                       // NN
  int*   CNT     = (int*)(wsf + 512 + NN);          // NN
  float* EW      = wsf + 512 + 2 * NN;              // NE
  int*   PTR     = (int*)(EW + NE);                 // NN+1
  int*   FILL    = PTR + NN + 1;                    // NN
  int*   BSUM    = FILL + NN;                       // 391 (pad 512)
  uint32_t* W2T  = (uint32_t*)(BSUM + 512);         // 8192
  float* PRM     = (float*)(W2T + 8192);            // 896 (+pad 2 -> even)
  int2*  EPK     = (int2*)(PRM + 898);              // NE int2 (8B aligned)
  float* H1      = (float*)(EPK + NE);              // NN*64
  uint32_t* MSK  = (uint32_t*)H1;                   // 8M words, dead before conv1

  hipMemsetAsync(bn_sums, 0, (512 + 2 * NN) * sizeof(float), stream);

  phase1<<<BN_BLOCKS + HIST_BLOCKS + MASK_WORDS / 256, 256, 0, stream>>>(
      edgenet, pw1, pb1, colp, bn_sums, CNT, MSK);

  csr_scanA<<<391, 256, 0, stream>>>(CNT, PTR, BSUM);
  csr_scanB<<<1, 512, 0, stream>>>(BSUM);
  csr_scanAdd<<<391, 256, 0, stream>>>(PTR, BSUM, FILL);

  phase2<<<HIST_BLOCKS + 33, 256, 0, stream>>>(rowp, colp, FILL, EPK, bn_sums,
                                               pw1, pb1, pgamma, pbeta, pw2,
                                               PRM, W2T);

  pae_edge<<<NE / 32, 256, 0, stream>>>(edgenet, PRM, W2T, pb2, colp, MSK, EW, DEG);
  csr_coef<<<(NE + 255) / 256, 256, 0, stream>>>(EPK, EW, DEG);

  conv1_fused<<<NN / 16, 256, 0, stream>>>(PTR, EPK, DEG, x, c1w, c1b, H1);
  conv2_head<<<NN / 16, 256, 0, stream>>>(PTR, EPK, DEG, H1, c2w, c2b,
                                          l1w, l1b, l2w, l2b, out);
}

// Round 7
// 1064.253 us; speedup vs baseline: 1.3167x; 1.1474x over previous
//
#include <hip/hip_runtime.h>
#include <stdint.h>

// ---------------------------------------------------------------------------
// Node_GCN: PAE edge weights (MLP+BN+dropout+cosine) -> 2x GCNConv -> MLP head
// R7: the 256M-call threefry is a ~600us VALU wall (measured R5/R6) — so
// maximize work hidden UNDER it: one "mega" launch interleaves (mod-47)
// 31250 inline-threefry pae blocks + 3907 csr_fill blocks + 1563 XW1=x@c1w
// GEMM blocks (legal: gather(x)@W == gather(x@W)). conv1 becomes pure gather
// (1 wave/node, unroll-2), H1 stored bf16. scanB/scanAdd/w2prep/bn_finalize
// merged. 7 launches, ws ~52 MB.
// ---------------------------------------------------------------------------

#define NN 100000
#define NE 1000000
#define INV_KEEP (1.0f/0.7f)
// uniform(bits) < 0.7  <=>  bits < 5872026<<9   (0.7f = 0x3F333333 exactly)
#define KEEP_THR 3006477312u

#define BN_BLOCKS   1000
#define HIST_BLOCKS 3907
#define PAE_BLOCKS  31250   // NE/32
#define XW1_BLOCKS  1563    // ceil(NN/64)
#define MEGA_GROUPS 782     // ceil(PAE_BLOCKS/40)
#define MEGA_BLOCKS (MEGA_GROUPS * 47)

typedef short bf16x8 __attribute__((ext_vector_type(8)));
typedef float f32x4  __attribute__((ext_vector_type(4)));
typedef uint32_t u32x4 __attribute__((ext_vector_type(4)));

// ---- threefry2x32 (20 rounds), exact jax/_src/prng.py semantics -----------
__host__ __device__ constexpr uint32_t rotl32c(uint32_t x, int r) {
  return (x << r) | (x >> (32 - r));
}

struct TFK { uint32_t a, b; };
__host__ __device__ constexpr TFK tf_const(uint32_t k0, uint32_t k1,
                                           uint32_t x0, uint32_t x1) {
  uint32_t k2 = k0 ^ k1 ^ 0x1BD11BDAu;
  x0 += k0; x1 += k1;
#define TFC_R(r) { x0 += x1; x1 = rotl32c(x1, (r)); x1 ^= x0; }
  TFC_R(13) TFC_R(15) TFC_R(26) TFC_R(6)   x0 += k1; x1 += k2 + 1u;
  TFC_R(17) TFC_R(29) TFC_R(16) TFC_R(24)  x0 += k2; x1 += k0 + 2u;
  TFC_R(13) TFC_R(15) TFC_R(26) TFC_R(6)   x0 += k0; x1 += k1 + 3u;
  TFC_R(17) TFC_R(29) TFC_R(16) TFC_R(24)  x0 += k1; x1 += k2 + 4u;
  TFC_R(13) TFC_R(15) TFC_R(26) TFC_R(6)   x0 += k2; x1 += k0 + 5u;
#undef TFC_R
  return TFK{x0, x1};
}

// keys from jax.random.split(jax.random.key(42)), partitionable mode
constexpr TFK KP = tf_const(0u, 42u, 0u, 0u);
constexpr TFK KH = tf_const(0u, 42u, 0u, 1u);

// partitionable random bits for element idx: threefry(key,(0,idx)) -> o0^o1
template <uint32_t K0, uint32_t K1>
__device__ __forceinline__ uint32_t tf_bits(uint32_t idx) {
  constexpr uint32_t K2 = K0 ^ K1 ^ 0x1BD11BDAu;
  uint32_t x0 = K0;
  uint32_t x1 = idx + K1;
#define TF_R(r) { x0 += x1; \
    x1 = __builtin_amdgcn_alignbit(x1, x1, 32u - (r)) ^ x0; }
  TF_R(13) TF_R(15) TF_R(26) TF_R(6)   x0 += K1; x1 += K2 + 1u;
  TF_R(17) TF_R(29) TF_R(16) TF_R(24)  x0 += K2; x1 += K0 + 2u;
  TF_R(13) TF_R(15) TF_R(26) TF_R(6)   x0 += K0; x1 += K1 + 3u;
  TF_R(17) TF_R(29) TF_R(16) TF_R(24)  x0 += K1; x1 += K2 + 4u;
  TF_R(13) TF_R(15) TF_R(26) TF_R(6)   x0 += K2; x1 += K0 + 5u;
#undef TF_R
  return x0 ^ x1;
}

__device__ __forceinline__ uint16_t f2bf(float f) {  // RNE
  uint32_t u = __float_as_uint(f);
  return (uint16_t)((u + 0x7FFFu + ((u >> 16) & 1u)) >> 16);
}

__device__ __forceinline__ float bf2f(uint16_t u) {
  return __uint_as_float((uint32_t)u << 16);
}

// ---------------------------------------------------------------------------
// K1: phase1 = bn_stats (blocks 0..999) + csr_hist (1000..4906).
// ---------------------------------------------------------------------------
__global__ __launch_bounds__(256) void phase1(const float* __restrict__ edgenet,
                                              const float* __restrict__ w1,
                                              const float* __restrict__ b1,
                                              const int* __restrict__ colp,
                                              float* __restrict__ sums,
                                              int* __restrict__ cnt) {
  int b = blockIdx.x;
  int t = threadIdx.x;
  if (b < BN_BLOCKS) {
    int c = t & 127, g = t >> 7;
    float wA = w1[c], wB = w1[128 + c], bb = b1[c];
    const float4* ed4 = (const float4*)edgenet;
    int e0 = b * 1000;
    float s0 = 0.f, q0 = 0.f, s1 = 0.f, q1 = 0.f;
#pragma unroll 4
    for (int e = g; e < 1000; e += 2) {
      float4 x = ed4[e0 + e];
      float h = fmaxf(fmaf(x.y, wB, fmaf(x.x, wA, bb)), 0.f);
      s0 += h; q0 = fmaf(h, h, q0);
      h = fmaxf(fmaf(x.w, wB, fmaf(x.z, wA, bb)), 0.f);
      s1 += h; q1 = fmaf(h, h, q1);
    }
    atomicAdd(&sums[c], s0);
    atomicAdd(&sums[256 + c], q0);
    atomicAdd(&sums[128 + c], s1);
    atomicAdd(&sums[384 + c], q1);
  } else {
    int e = (b - BN_BLOCKS) * 256 + t;
    if (e < NE) atomicAdd(&cnt[colp[e]], 1);
  }
}

// ---------------------------------------------------------------------------
// K2: scanA — per-block exclusive scan of cnt into ptr, block totals to bsum.
// ---------------------------------------------------------------------------
__global__ __launch_bounds__(256) void csr_scanA(const int* __restrict__ cnt,
                                                 int* __restrict__ ptr,
                                                 int* __restrict__ bsum) {
  __shared__ int sh[256];
  int t = threadIdx.x;
  int i = blockIdx.x * 256 + t;
  int x = (i < NN) ? cnt[i] : 0;
  sh[t] = x;
  __syncthreads();
  for (int o = 1; o < 256; o <<= 1) {
    int v = (t >= o) ? sh[t - o] : 0;
    __syncthreads();
    sh[t] += v;
    __syncthreads();
  }
  if (i < NN) ptr[i] = sh[t] - x;
  if (t == 255) bsum[blockIdx.x] = sh[255];
}

// ---------------------------------------------------------------------------
// K3: scanAddPrep (512 thr). Blocks 0..390: redundant LDS scan of bsum[391]
// + apply prefix -> final PTR/FILL. Blocks 391..406: w2->bf16 [n][k].
// Block 407: bn_finalize -> PRM.
// PRM (896 floats): [0]wA [128]wB [256]b1 [384]aK[256] [640]bK[256]
// ---------------------------------------------------------------------------
__global__ __launch_bounds__(512) void scanAddPrep(const int* __restrict__ bsum,
                                                   int* __restrict__ ptr,
                                                   int* __restrict__ fill,
                                                   const float* __restrict__ sums,
                                                   const float* __restrict__ w1,
                                                   const float* __restrict__ b1,
                                                   const float* __restrict__ gamma,
                                                   const float* __restrict__ beta,
                                                   const float* __restrict__ w2,
                                                   float* __restrict__ prm,
                                                   uint32_t* __restrict__ w2t) {
  int b = blockIdx.x;
  int t = threadIdx.x;
  if (b < 391) {
    __shared__ int sh[512];
    int x = (t < 391) ? bsum[t] : 0;
    sh[t] = x;
    __syncthreads();
    for (int o = 1; o < 512; o <<= 1) {
      int v = (t >= o) ? sh[t - o] : 0;
      __syncthreads();
      sh[t] += v;
      __syncthreads();
    }
    int excl = (b == 0) ? 0 : sh[b - 1];
    if (t < 256) {
      int i = b * 256 + t;
      if (i < NN) {
        int v = ptr[i] + excl;
        ptr[i] = v;
        fill[i] = v;
        if (i == NN - 1) ptr[NN] = NE;
      }
    }
  } else if (b < 407) {
    int i = (b - 391) * 512 + t;   // < 8192, one uint = 2 bf16 along k
    int n = i >> 6, kp = i & 63;
    float f0 = w2[(2 * kp) * 128 + n];
    float f1 = w2[(2 * kp + 1) * 128 + n];
    w2t[i] = (uint32_t)f2bf(f0) | ((uint32_t)f2bf(f1) << 16);
  } else if (t < 256) {
    int c = t & 127;
    const float invE = 1.0f / (float)NE;
    float mean = sums[t] * invE;
    float var = fmaxf(sums[256 + t] * invE - mean * mean, 0.f);
    float rstd = rsqrtf(var + 1e-5f);
    float a = gamma[c] * rstd;
    prm[384 + t] = a * INV_KEEP;
    prm[640 + t] = (beta[c] - mean * a) * INV_KEEP;
    if (t < 128) { prm[t] = w1[t]; prm[128 + t] = w1[128 + t]; prm[256 + t] = b1[t]; }
  }
}

// ---------------------------------------------------------------------------
// K4: mega — interleaved roles, g = b%47:
//   g<40 : pae (inline threefry, MFMA, cosine, deg atomic)   [VALU wall]
//   g<45 : csr_fill -> EPK=(row,e)                            [memory]
//   else : XW1 = x @ c1w (64 nodes/block)                     [memory/LDS]
// ---------------------------------------------------------------------------
__global__ __launch_bounds__(256, 3) void mega(const float* __restrict__ edgenet,
                                               const float* __restrict__ prm_g,
                                               const uint32_t* __restrict__ w2t,
                                               const float* __restrict__ b2,
                                               const int* __restrict__ rowp,
                                               const int* __restrict__ colp,
                                               float* __restrict__ ew_out,
                                               float* __restrict__ deg,
                                               int* __restrict__ fill,
                                               int2* __restrict__ epk,
                                               const float* __restrict__ x,
                                               const float* __restrict__ c1w,
                                               float* __restrict__ xw1) {
  __shared__ __align__(16) uint8_t smem[38912];
  int b = blockIdx.x;
  int t = threadIdx.x;
  int g = b % 47, u = b / 47;

  if (g < 40) {
    // ---------------- pae role ----------------
    int blk = u * 40 + g;
    if (blk >= PAE_BLOCKS) return;
    uint16_t* w2s = (uint16_t*)smem;                 // 128*136*2 = 34816 B
    float* prm    = (float*)(smem + 34816);          // 896*4 = 3584 B
    float* b2s    = (float*)(smem + 38400);          // 512 B
    int e0 = blk * 32;
    for (int i = t; i < 8192; i += 256) {
      int n = i >> 6, kp = i & 63;
      *(uint32_t*)&w2s[n * 136 + 2 * kp] = w2t[i];
    }
    for (int i = t; i < 896; i += 256) prm[i] = prm_g[i];
    if (t < 128) b2s[t] = b2[t];
    __syncthreads();

    int lane = t & 63, w = t >> 6;
    int cl = lane & 15, quad = lane >> 4;
    int quad8 = quad * 8;
    int row = 16 * w + cl;
    int el = row >> 1, s = row & 1;
    int so = s << 7;
    float2 xv = *(const float2*)&edgenet[(size_t)(e0 + el) * 4 + 2 * s];
    uint32_t rowbase = (uint32_t)(e0 + el) * 128u + (s ? 128000000u : 0u);

    f32x4 acc[8];
#pragma unroll
    for (int nt = 0; nt < 8; ++nt) acc[nt] = (f32x4){0.f, 0.f, 0.f, 0.f};

#pragma unroll
    for (int kt = 0; kt < 4; ++kt) {
      int c0 = kt * 32 + quad8;
      uint32_t idxbase = rowbase + (uint32_t)c0;
      float wa[8], wb[8], bb[8], ak[8], bk[8];
      *(float4*)&wa[0] = *(const float4*)&prm[c0];
      *(float4*)&wa[4] = *(const float4*)&prm[c0 + 4];
      *(float4*)&wb[0] = *(const float4*)&prm[128 + c0];
      *(float4*)&wb[4] = *(const float4*)&prm[132 + c0];
      *(float4*)&bb[0] = *(const float4*)&prm[256 + c0];
      *(float4*)&bb[4] = *(const float4*)&prm[260 + c0];
      *(float4*)&ak[0] = *(const float4*)&prm[384 + so + c0];
      *(float4*)&ak[4] = *(const float4*)&prm[388 + so + c0];
      *(float4*)&bk[0] = *(const float4*)&prm[640 + so + c0];
      *(float4*)&bk[4] = *(const float4*)&prm[644 + so + c0];
      uint32_t pk[4];
#pragma unroll
      for (int jp = 0; jp < 4; ++jp) {
        uint32_t uu[2];
#pragma unroll
        for (int q = 0; q < 2; ++q) {
          int j = 2 * jp + q;
          float h = fmaxf(fmaf(xv.y, wb[j], fmaf(xv.x, wa[j], bb[j])), 0.f);
          float hn = fmaf(h, ak[j], bk[j]);
          uint32_t bits = tf_bits<KP.a, KP.b>(idxbase + (uint32_t)j);
          float hd = (bits < KEEP_THR) ? hn : 0.f;
          uu[q] = __float_as_uint(hd) + 0x8000u;
        }
        pk[jp] = __builtin_amdgcn_perm(uu[1], uu[0], 0x07060302u);
      }
      u32x4 pkv = {pk[0], pk[1], pk[2], pk[3]};
      bf16x8 afr = __builtin_bit_cast(bf16x8, pkv);
      const uint16_t* bbase = &w2s[(size_t)c0];
#pragma unroll
      for (int nt = 0; nt < 8; ++nt) {
        bf16x8 bfr = *(const bf16x8*)&bbase[(nt * 16 + cl) * 136];
        acc[nt] = __builtin_amdgcn_mfma_f32_16x16x32_bf16(afr, bfr, acc[nt], 0, 0, 0);
      }
    }

    float p11[2] = {0.f, 0.f}, p22[2] = {0.f, 0.f}, p12[2] = {0.f, 0.f};
#pragma unroll
    for (int nt = 0; nt < 8; ++nt) {
      float bv = b2s[nt * 16 + cl];
#pragma unroll
      for (int uq = 0; uq < 2; ++uq) {
        float v1 = acc[nt][2 * uq] + bv;
        float v2 = acc[nt][2 * uq + 1] + bv;
        p11[uq] = fmaf(v1, v1, p11[uq]);
        p22[uq] = fmaf(v2, v2, p22[uq]);
        p12[uq] = fmaf(v1, v2, p12[uq]);
      }
    }
#pragma unroll
    for (int uq = 0; uq < 2; ++uq) {
      float a = p11[uq], bq = p22[uq], d = p12[uq];
      for (int off = 1; off < 16; off <<= 1) {
        a += __shfl_xor(a, off, 64);
        bq += __shfl_xor(bq, off, 64);
        d += __shfl_xor(d, off, 64);
      }
      if (cl == 0) {
        int e = e0 + 8 * w + 2 * quad + uq;
        float n1 = fmaxf(sqrtf(a), 1e-8f);
        float n2 = fmaxf(sqrtf(bq), 1e-8f);
        float ew = (d / (n1 * n2) + 1.f) * 0.5f;
        ew_out[e] = ew;
        atomicAdd(&deg[colp[e]], ew);
      }
    }
  } else if (g < 45) {
    // ---------------- csr_fill role ----------------
    int blk = u * 5 + (g - 40);
    if (blk >= HIST_BLOCKS) return;
    int e = blk * 256 + t;
    if (e < NE) {
      int r = rowp[e];
      int p = atomicAdd(&fill[colp[e]], 1);
      epk[p] = make_int2(r, e);
    }
  } else {
    // ---------------- XW1 = x @ c1w role ----------------
    int blk = u * 2 + (g - 45);
    if (blk >= XW1_BLOCKS) return;
    float* InT = (float*)smem;                 // 64*68*4 = 17408 B
    float* Wl  = (float*)(smem + 17408);       // 64*64*4 = 16384 B
    int v0 = blk * 64;
    for (int i = t; i < 4096; i += 256) {
      Wl[i] = c1w[i];
      int v = i >> 6, k = i & 63;
      int vv = min(v0 + v, NN - 1);
      InT[k * 68 + v] = x[(size_t)vv * 64 + k];
    }
    __syncthreads();
    int tx = t & 15, ty = t >> 4;
    float acc[4][4];
#pragma unroll
    for (int i = 0; i < 4; ++i)
#pragma unroll
      for (int j = 0; j < 4; ++j) acc[i][j] = 0.f;
#pragma unroll 4
    for (int k = 0; k < 64; ++k) {
      float4 av = *(const float4*)&InT[k * 68 + 4 * ty];
      float4 bv = *(const float4*)&Wl[k * 64 + 4 * tx];
      float a4[4] = {av.x, av.y, av.z, av.w};
      float b4[4] = {bv.x, bv.y, bv.z, bv.w};
#pragma unroll
      for (int i = 0; i < 4; ++i)
#pragma unroll
        for (int j = 0; j < 4; ++j) acc[i][j] = fmaf(a4[i], b4[j], acc[i][j]);
    }
    for (int i = 0; i < 4; ++i) {
      int v = v0 + 4 * ty + i;
      if (v < NN)
        *(float4*)&xw1[(size_t)v * 64 + 4 * tx] =
            make_float4(acc[i][0], acc[i][1], acc[i][2], acc[i][3]);
    }
  }
}

// ---------------------------------------------------------------------------
// K5: csr_coef: EPK[p]=(r,e) -> (r, dinv_r*ew[e]) in place.
// ---------------------------------------------------------------------------
__global__ void csr_coef(int2* __restrict__ epk, const float* __restrict__ ew,
                         const float* __restrict__ deg) {
  int p = blockIdx.x * 256 + threadIdx.x;
  if (p < NE) {
    int2 pk = epk[p];
    float cf = rsqrtf(deg[pk.x] + 1.0f) * ew[pk.y];
    epk[p] = make_int2(pk.x, __float_as_int(cf));
  }
}

// ---------------------------------------------------------------------------
// K6: conv1 gather (on XW1): one wave per node, lane = channel, unroll-2.
// H1 (bf16) = relu(dinv*sum cf*XW1[r] + dinv^2*XW1[v] + bias)
// ---------------------------------------------------------------------------
__global__ __launch_bounds__(256) void conv1g(const int* __restrict__ ptr,
                                              const int2* __restrict__ epk,
                                              const float* __restrict__ deg,
                                              const float* __restrict__ xw,
                                              const float* __restrict__ bias,
                                              uint16_t* __restrict__ h1) {
  int t = threadIdx.x;
  int v = blockIdx.x * 4 + (t >> 6);
  int c = t & 63;
  int p = ptr[v], end = ptr[v + 1];
  float acc = 0.f;
  while (p + 2 <= end) {
    int2 a = epk[p];
    int2 bq = epk[p + 1];
    float xa = xw[(size_t)a.x * 64 + c];
    float xb = xw[(size_t)bq.x * 64 + c];
    acc = fmaf(__int_as_float(a.y), xa, acc);
    acc = fmaf(__int_as_float(bq.y), xb, acc);
    p += 2;
  }
  if (p < end) {
    int2 a = epk[p];
    acc = fmaf(__int_as_float(a.y), xw[(size_t)a.x * 64 + c], acc);
  }
  float dv = rsqrtf(deg[v] + 1.0f);
  float val = fmaf(dv, acc, fmaf(dv * dv, xw[(size_t)v * 64 + c], bias[c]));
  h1[(size_t)v * 64 + c] = f2bf(fmaxf(val, 0.f));
}

// ---------------------------------------------------------------------------
// K7: conv2 + full MLP head fused (h1 in bf16), unroll-2 gather.
// ---------------------------------------------------------------------------
__global__ __launch_bounds__(256) void conv2_head(const int* __restrict__ ptr,
                                                  const int2* __restrict__ epk,
                                                  const float* __restrict__ deg,
                                                  const uint16_t* __restrict__ h1,
                                                  const float* __restrict__ W,
                                                  const float* __restrict__ bias,
                                                  const float* __restrict__ l1w,
                                                  const float* __restrict__ l1b,
                                                  const float* __restrict__ l2w,
                                                  const float* __restrict__ l2b,
                                                  float* __restrict__ out) {
  __shared__ __align__(16) float Ws[4096];     // c2w [k][c']
  __shared__ __align__(16) float T[16 * 68];   // gather out, later reused as M
  __shared__ __align__(16) float H2[16 * 68];
  __shared__ float L1s[64 * 33];               // [k][j]
  __shared__ float L2s[320];                   // [j][f]
  __shared__ float biass[64], l1bs[32], l2bs[16];
  int t = threadIdx.x;
  for (int i = t; i < 4096; i += 256) Ws[i] = W[i];
  for (int i = t; i < 2048; i += 256) {
    int k = i >> 5, j = i & 31;
    L1s[k * 33 + j] = l1w[i];
  }
  for (int i = t; i < 320; i += 256) L2s[i] = l2w[i];
  if (t < 64) biass[t] = bias[t];
  if (t < 32) l1bs[t] = l1b[t];
  if (t < 10) l2bs[t] = l2b[t];
  int w = t >> 6, c = t & 63;
  int v0 = blockIdx.x * 16;
#pragma unroll 1
  for (int i = 0; i < 4; ++i) {
    int n = 4 * w + i;
    int v = v0 + n;
    int p = ptr[v], end = ptr[v + 1];
    float acc = 0.f;
    while (p + 2 <= end) {
      int2 a = epk[p];
      int2 bq = epk[p + 1];
      float xa = bf2f(h1[(size_t)a.x * 64 + c]);
      float xb = bf2f(h1[(size_t)bq.x * 64 + c]);
      acc = fmaf(__int_as_float(a.y), xa, acc);
      acc = fmaf(__int_as_float(bq.y), xb, acc);
      p += 2;
    }
    if (p < end) {
      int2 a = epk[p];
      acc = fmaf(__int_as_float(a.y), bf2f(h1[(size_t)a.x * 64 + c]), acc);
    }
    float dv = rsqrtf(deg[v] + 1.0f);
    T[n * 68 + c] = fmaf(dv, acc, dv * dv * bf2f(h1[(size_t)v * 64 + c]));
  }
  __syncthreads();
  {
    int n = t >> 4, cq = (t & 15) * 4;
    float4 o = *(const float4*)&biass[cq];
#pragma unroll 4
    for (int k = 0; k < 64; ++k) {
      float a = T[n * 68 + k];
      float4 wv = *(const float4*)&Ws[k * 64 + cq];
      o.x = fmaf(a, wv.x, o.x);
      o.y = fmaf(a, wv.y, o.y);
      o.z = fmaf(a, wv.z, o.z);
      o.w = fmaf(a, wv.w, o.w);
    }
    o.x = fmaxf(o.x, 0.f); o.y = fmaxf(o.y, 0.f);
    o.z = fmaxf(o.z, 0.f); o.w = fmaxf(o.w, 0.f);
    __syncthreads();
    *(float4*)&H2[n * 68 + cq] = o;
  }
  __syncthreads();
  {
    int n = t >> 4, j0 = t & 15;
#pragma unroll
    for (int jj = 0; jj < 2; ++jj) {
      int j = j0 + 16 * jj;
      float m = l1bs[j];
#pragma unroll 4
      for (int k = 0; k < 64; ++k) m = fmaf(H2[n * 68 + k], L1s[k * 33 + j], m);
      m = fmaxf(m, 0.f);
      uint32_t idx = (uint32_t)(v0 + n) * 32u + (uint32_t)j;
      bool kp = tf_bits<KH.a, KH.b>(idx) < KEEP_THR;
      T[n * 33 + j] = kp ? m * INV_KEEP : 0.f;
    }
  }
  __syncthreads();
  if (t < 160) {
    int n = t / 10, f = t % 10;
    float s = l2bs[f];
#pragma unroll
    for (int j = 0; j < 32; ++j) s = fmaf(T[n * 33 + j], L2s[j * 10 + f], s);
    out[(size_t)(v0 + n) * 10 + f] = s;
  }
}

// ---------------------------------------------------------------------------
extern "C" void kernel_launch(void* const* d_in, const int* in_sizes, int n_in,
                              void* d_out, int out_size, void* d_ws, size_t ws_size,
                              hipStream_t stream) {
  const float* x       = (const float*)d_in[0];
  const int*   ei      = (const int*)d_in[1];
  const float* edgenet = (const float*)d_in[2];
  const float* pw1     = (const float*)d_in[3];
  const float* pb1     = (const float*)d_in[4];
  const float* pgamma  = (const float*)d_in[5];
  const float* pbeta   = (const float*)d_in[6];
  const float* pw2     = (const float*)d_in[7];
  const float* pb2     = (const float*)d_in[8];
  const float* c1w     = (const float*)d_in[9];
  const float* c1b     = (const float*)d_in[10];
  const float* c2w     = (const float*)d_in[11];
  const float* c2b     = (const float*)d_in[12];
  const float* l1w     = (const float*)d_in[13];
  const float* l1b     = (const float*)d_in[14];
  const float* l2w     = (const float*)d_in[15];
  const float* l2b     = (const float*)d_in[16];
  float* out = (float*)d_out;

  const int* rowp = ei;
  const int* colp = ei + NE;

  // workspace (floats); zero region [bn_sums, DEG, CNT] contiguous
  float* wsf      = (float*)d_ws;
  float* bn_sums  = wsf;                              // 512
  float* DEG      = wsf + 512;                        // NN
  int*   CNT      = (int*)(wsf + 512 + NN);           // NN
  float* EW       = wsf + 512 + 2 * NN;               // NE
  int*   PTR      = (int*)(EW + NE);                  // NN+1
  int*   FILL     = PTR + NN + 1;                     // NN
  int*   BSUM     = FILL + NN;                        // 391 (pad 512)
  uint32_t* W2T   = (uint32_t*)(BSUM + 512);          // 8192
  float* PRM      = (float*)(W2T + 8192);             // 896 (pad 898)
  int2*  EPK      = (int2*)(PRM + 898);               // NE int2 (8 MB)
  float* XW1      = (float*)(EPK + NE);               // NN*64 fp32 (25.6 MB)
  uint16_t* H1    = (uint16_t*)(XW1 + (size_t)NN * 64); // NN*64 bf16 (12.8 MB)

  hipMemsetAsync(bn_sums, 0, (512 + 2 * NN) * sizeof(float), stream);

  phase1<<<BN_BLOCKS + HIST_BLOCKS, 256, 0, stream>>>(edgenet, pw1, pb1, colp,
                                                      bn_sums, CNT);
  csr_scanA<<<391, 256, 0, stream>>>(CNT, PTR, BSUM);
  scanAddPrep<<<408, 512, 0, stream>>>(BSUM, PTR, FILL, bn_sums, pw1, pb1,
                                       pgamma, pbeta, pw2, PRM, W2T);

  mega<<<MEGA_BLOCKS, 256, 0, stream>>>(edgenet, PRM, W2T, pb2, rowp, colp,
                                        EW, DEG, FILL, EPK, x, c1w, XW1);

  csr_coef<<<(NE + 255) / 256, 256, 0, stream>>>(EPK, EW, DEG);

  conv1g<<<NN / 4, 256, 0, stream>>>(PTR, EPK, DEG, XW1, c1b, H1);
  conv2_head<<<NN / 16, 256, 0, stream>>>(PTR, EPK, DEG, H1, c2w, c2b,
                                          l1w, l1b, l2w, l2b, out);
}